// Round 4
// baseline (682.958 us; speedup 1.0000x reference)
//
#include <hip/hip_runtime.h>

#define N_NODES 20000
#define N_EDGES 320000
#define N_REL   100
#define FDIM    256
#define NHEAD   8
#define HDIM    32
#define SCAN_BLOCKS ((N_NODES + 255) / 256)   // 79

using short8 = __attribute__((ext_vector_type(8))) short;   // 8 bf16 in 4 VGPRs
using f32x4  = __attribute__((ext_vector_type(4))) float;

__device__ inline unsigned short f2bf(float f) {
    union { float f; unsigned int u; } v; v.f = f;
    unsigned int r = v.u + 0x7fff + ((v.u >> 16) & 1);   // RNE
    return (unsigned short)(r >> 16);
}
__device__ inline float bf2f(unsigned short u) {
    union { unsigned int i; float f; } v; v.i = ((unsigned int)u) << 16; return v.f;
}
__device__ inline float4 bf4(ushort4 u) {
    return make_float4(bf2f(u.x), bf2f(u.y), bf2f(u.z), bf2f(u.w));
}
__device__ inline float bf_lo(unsigned int u) {
    union { unsigned int i; float f; } v; v.i = u << 16; return v.f;
}
__device__ inline float bf_hi(unsigned int u) {
    union { unsigned int i; float f; } v; v.i = u & 0xffff0000u; return v.f;
}
// direct global -> LDS DMA, 16 bytes per lane (gfx950 global_load_lds_dwordx4)
__device__ __forceinline__ void g2lds16(const unsigned short* g, unsigned short* l) {
    __builtin_amdgcn_global_load_lds(
        (const __attribute__((address_space(1))) unsigned int*)g,
        (__attribute__((address_space(3))) unsigned int*)l,
        16, 0, 0);
}

// bijective XCD swizzle (m204)
__device__ inline void xcd_tile(int* m0, int* n0, int tm, int tn) {
    int nwg  = gridDim.x * gridDim.y;
    int wgid = blockIdx.x + blockIdx.y * gridDim.x;
    int q = nwg >> 3, r = nwg & 7;
    int xcd = wgid & 7, pos = wgid >> 3;
    int nid = (xcd < r ? xcd * (q + 1) : r * (q + 1) + (xcd - r) * q) + pos;
    int gy = gridDim.y;
    int bx = nid / gy;
    int by = nid - bx * gy;
    *m0 = bx * tm;
    *n0 = by * tn;
}

// ---------------------------------------------------------------------------
// LayerNorm over 256 features -> bf16 output. One wave per row.
// ---------------------------------------------------------------------------
__global__ __launch_bounds__(64) void ln_bf16_kernel(
    const float* __restrict__ in, const float* __restrict__ g,
    const float* __restrict__ b, unsigned short* __restrict__ out, int rows)
{
    int row = blockIdx.x;
    if (row >= rows) return;
    int tid = threadIdx.x;
    const float4 v = *(const float4*)(in + (size_t)row * FDIM + tid * 4);
    float s = v.x + v.y + v.z + v.w;
    float q = v.x * v.x + v.y * v.y + v.z * v.z + v.w * v.w;
    #pragma unroll
    for (int d = 1; d < 64; d <<= 1) { s += __shfl_xor(s, d); q += __shfl_xor(q, d); }
    float mean = s * (1.0f / FDIM);
    float var  = q * (1.0f / FDIM) - mean * mean;
    float inv  = rsqrtf(var + 1e-5f);
    float4 gg = *(const float4*)(g + tid * 4);
    float4 bb = *(const float4*)(b + tid * 4);
    ushort4 o;
    o.x = f2bf((v.x - mean) * inv * gg.x + bb.x);
    o.y = f2bf((v.y - mean) * inv * gg.y + bb.y);
    o.z = f2bf((v.z - mean) * inv * gg.z + bb.z);
    o.w = f2bf((v.w - mean) * inv * gg.w + bb.w);
    *(ushort4*)(out + (size_t)row * FDIM + tid * 4) = o;
}

// rst = bf2f(feat) + ent (fp32) ; y = LN(rst) (bf16)
__global__ __launch_bounds__(64) void rst_ln_kernel(
    const unsigned short* __restrict__ feat, const float* __restrict__ ent,
    const float* __restrict__ g, const float* __restrict__ b,
    float* __restrict__ rst, unsigned short* __restrict__ y)
{
    int row = blockIdx.x;
    int tid = threadIdx.x;
    const float4 f = bf4(*(const ushort4*)(feat + (size_t)row * FDIM + tid * 4));
    const float4 e = *(const float4*)(ent + (size_t)row * FDIM + tid * 4);
    float4 r;
    r.x = f.x + e.x; r.y = f.y + e.y; r.z = f.z + e.z; r.w = f.w + e.w;
    *(float4*)(rst + (size_t)row * FDIM + tid * 4) = r;
    float s = r.x + r.y + r.z + r.w;
    float q = r.x * r.x + r.y * r.y + r.z * r.z + r.w * r.w;
    #pragma unroll
    for (int d = 1; d < 64; d <<= 1) { s += __shfl_xor(s, d); q += __shfl_xor(q, d); }
    float mean = s * (1.0f / FDIM);
    float var  = q * (1.0f / FDIM) - mean * mean;
    float inv  = rsqrtf(var + 1e-5f);
    float4 gg = *(const float4*)(g + tid * 4);
    float4 bb = *(const float4*)(b + tid * 4);
    ushort4 o;
    o.x = f2bf((r.x - mean) * inv * gg.x + bb.x);
    o.y = f2bf((r.y - mean) * inv * gg.y + bb.y);
    o.z = f2bf((r.z - mean) * inv * gg.z + bb.z);
    o.w = f2bf((r.w - mean) * inv * gg.w + bb.w);
    *(ushort4*)(y + (size_t)row * FDIM + tid * 4) = o;
}

// Wt[n*K + k] = bf16(W[k*N + n])
__global__ void transpose_bf16_kernel(const float* __restrict__ W,
                                      unsigned short* __restrict__ Wt, int K, int N)
{
    int idx = blockIdx.x * 256 + threadIdx.x;
    if (idx >= K * N) return;
    int n = idx / K, k = idx - n * K;
    Wt[idx] = f2bf(W[(size_t)k * N + n]);
}

// ---------------------------------------------------------------------------
// bf16 MFMA GEMM (B^T): C[M,N] = A[M,K] @ Bt[N,K]^T  (+bias)(relu)(+add)
// 128x128 tile, 4 waves, 4x4 16x16x32 frags/wave, BK=32.
// Double-buffered LDS + single barrier per K-step + XCD-aware swizzle.
// ---------------------------------------------------------------------------
__global__ __launch_bounds__(256) void mfma_gemm_bt(
    const unsigned short* __restrict__ A, const unsigned short* __restrict__ Bt,
    const float* __restrict__ bias, const float* __restrict__ add,
    float* __restrict__ Cf, unsigned short* __restrict__ Cb,
    int M, int K, int N, int relu)
{
    __shared__ unsigned short As[2][128 * 32];
    __shared__ unsigned short Bs[2][128 * 32];
    int tid  = threadIdx.x;
    int wave = tid >> 6, lane = tid & 63;
    int quad = lane >> 4, l16 = lane & 15;
    int m0, n0;
    xcd_tile(&m0, &n0, 128, 128);
    int wr = (wave >> 1) * 64, wc = (wave & 1) * 64;

    f32x4 acc[4][4] = {};

    int cA = tid, cB = tid + 256;
    int rA0 = cA >> 2, kA0 = (cA & 3) * 8;
    int rB0 = cB >> 2, kB0 = (cB & 3) * 8;
    int rA = m0 + rA0; if (rA >= M) rA = M - 1;
    int rB = m0 + rB0; if (rB >= M) rB = M - 1;
    const unsigned short* gA0 = A + (size_t)rA * K + kA0;
    const unsigned short* gA1 = A + (size_t)rB * K + kB0;
    const unsigned short* gB0 = Bt + (size_t)(n0 + rA0) * K + kA0;
    const unsigned short* gB1 = Bt + (size_t)(n0 + rB0) * K + kB0;

    g2lds16(gA0, As[0] + cA * 8);
    g2lds16(gA1, As[0] + cB * 8);
    g2lds16(gB0, Bs[0] + cA * 8);
    g2lds16(gB1, Bs[0] + cB * 8);
    __syncthreads();

    int cur = 0;
    for (int k0 = 0; k0 < K; k0 += 32) {
        int k1 = k0 + 32;
        if (k1 < K) {
            int nb = cur ^ 1;
            g2lds16(gA0 + k1, As[nb] + cA * 8);
            g2lds16(gA1 + k1, As[nb] + cB * 8);
            g2lds16(gB0 + k1, Bs[nb] + cA * 8);
            g2lds16(gB1 + k1, Bs[nb] + cB * 8);
        }
        short8 af[4], bfr[4];
        #pragma unroll
        for (int i = 0; i < 4; ++i)
            af[i] = *(const short8*)(As[cur] + (wr + i * 16 + l16) * 32 + quad * 8);
        #pragma unroll
        for (int j = 0; j < 4; ++j)
            bfr[j] = *(const short8*)(Bs[cur] + (wc + j * 16 + l16) * 32 + quad * 8);
        #pragma unroll
        for (int i = 0; i < 4; ++i)
            #pragma unroll
            for (int j = 0; j < 4; ++j)
                acc[i][j] = __builtin_amdgcn_mfma_f32_16x16x32_bf16(
                    af[i], bfr[j], acc[i][j], 0, 0, 0);
        __syncthreads();
        cur ^= 1;
    }

    #pragma unroll
    for (int i = 0; i < 4; ++i) {
        #pragma unroll
        for (int j = 0; j < 4; ++j) {
            int col = n0 + wc + j * 16 + l16;
            float bsv = bias ? bias[col] : 0.0f;
            #pragma unroll
            for (int r = 0; r < 4; ++r) {
                int row = m0 + wr + i * 16 + quad * 4 + r;
                if (row < M) {
                    float v = acc[i][j][r] + bsv;
                    if (relu) v = fmaxf(v, 0.0f);
                    if (add)  v += add[(size_t)row * N + col];
                    if (Cf) Cf[(size_t)row * N + col] = v;
                    else    Cb[(size_t)row * N + col] = f2bf(v);
                }
            }
        }
    }
}

// ---------------------------------------------------------------------------
// 64x128-tile variant (small grids / long K, e.g. FFN2): 4 waves, 4x2 frags.
// ---------------------------------------------------------------------------
__global__ __launch_bounds__(256) void mfma_gemm64_bt(
    const unsigned short* __restrict__ A, const unsigned short* __restrict__ Bt,
    const float* __restrict__ bias, const float* __restrict__ add,
    float* __restrict__ Cf, int M, int K, int N)
{
    __shared__ unsigned short As[2][64 * 32];
    __shared__ unsigned short Bs[2][128 * 32];
    int tid  = threadIdx.x;
    int wave = tid >> 6, lane = tid & 63;
    int quad = lane >> 4, l16 = lane & 15;
    int m0, n0;
    xcd_tile(&m0, &n0, 64, 128);
    int wc = wave * 32;

    f32x4 acc[4][2] = {};

    int rA0 = tid >> 2, kA0 = (tid & 3) * 8;
    int cB0 = tid, cB1 = tid + 256;
    int rB0 = cB0 >> 2, kB0 = (cB0 & 3) * 8;
    int rB1 = cB1 >> 2, kB1 = (cB1 & 3) * 8;
    int rA = m0 + rA0; if (rA >= M) rA = M - 1;
    const unsigned short* gA  = A + (size_t)rA * K + kA0;
    const unsigned short* gB0 = Bt + (size_t)(n0 + rB0) * K + kB0;
    const unsigned short* gB1 = Bt + (size_t)(n0 + rB1) * K + kB1;

    g2lds16(gA,  As[0] + tid * 8);
    g2lds16(gB0, Bs[0] + cB0 * 8);
    g2lds16(gB1, Bs[0] + cB1 * 8);
    __syncthreads();

    int cur = 0;
    for (int k0 = 0; k0 < K; k0 += 32) {
        int k1 = k0 + 32;
        if (k1 < K) {
            int nb = cur ^ 1;
            g2lds16(gA + k1,  As[nb] + tid * 8);
            g2lds16(gB0 + k1, Bs[nb] + cB0 * 8);
            g2lds16(gB1 + k1, Bs[nb] + cB1 * 8);
        }
        short8 af[4], bfr[2];
        #pragma unroll
        for (int i = 0; i < 4; ++i)
            af[i] = *(const short8*)(As[cur] + (i * 16 + l16) * 32 + quad * 8);
        #pragma unroll
        for (int j = 0; j < 2; ++j)
            bfr[j] = *(const short8*)(Bs[cur] + (wc + j * 16 + l16) * 32 + quad * 8);
        #pragma unroll
        for (int i = 0; i < 4; ++i)
            #pragma unroll
            for (int j = 0; j < 2; ++j)
                acc[i][j] = __builtin_amdgcn_mfma_f32_16x16x32_bf16(
                    af[i], bfr[j], acc[i][j], 0, 0, 0);
        __syncthreads();
        cur ^= 1;
    }

    #pragma unroll
    for (int i = 0; i < 4; ++i) {
        #pragma unroll
        for (int j = 0; j < 2; ++j) {
            int col = n0 + wc + j * 16 + l16;
            float bsv = bias ? bias[col] : 0.0f;
            #pragma unroll
            for (int r = 0; r < 4; ++r) {
                int row = m0 + i * 16 + quad * 4 + r;
                if (row < M) {
                    float v = acc[i][j][r] + bsv;
                    if (add) v += add[(size_t)row * N + col];
                    Cf[(size_t)row * N + col] = v;
                }
            }
        }
    }
}

// ---------------------------------------------------------------------------
// Graph plumbing: degree count -> 3-phase parallel scan -> scatter
// ---------------------------------------------------------------------------
__global__ void count_kernel(const int* __restrict__ dst, int* __restrict__ deg, int E)
{
    int i = blockIdx.x * blockDim.x + threadIdx.x;
    if (i < E) atomicAdd(&deg[dst[i]], 1);
}

__global__ __launch_bounds__(256) void scan1_kernel(
    const int* __restrict__ deg, int* __restrict__ offsets, int* __restrict__ bsum, int n)
{
    __shared__ int tmp[256];
    int tid = threadIdx.x;
    int i = blockIdx.x * 256 + tid;
    int v = (i < n) ? deg[i] : 0;
    tmp[tid] = v;
    __syncthreads();
    for (int d = 1; d < 256; d <<= 1) {
        int u = (tid >= d) ? tmp[tid - d] : 0;
        __syncthreads();
        tmp[tid] += u;
        __syncthreads();
    }
    if (i < n) offsets[i] = tmp[tid] - v;
    if (tid == 255) bsum[blockIdx.x] = tmp[255];
}

__global__ __launch_bounds__(128) void scan2_kernel(int* __restrict__ bsum, int nb)
{
    __shared__ int tmp[128];
    int tid = threadIdx.x;
    int v = (tid < nb) ? bsum[tid] : 0;
    tmp[tid] = v;
    __syncthreads();
    for (int d = 1; d < 128; d <<= 1) {
        int u = (tid >= d) ? tmp[tid - d] : 0;
        __syncthreads();
        tmp[tid] += u;
        __syncthreads();
    }
    if (tid < nb) bsum[tid] = tmp[tid] - v;
}

__global__ __launch_bounds__(256) void scan3_kernel(
    const int* __restrict__ deg, int* __restrict__ offsets,
    const int* __restrict__ bsum, int* __restrict__ cursor,
    float* __restrict__ logdeg, int n, int E)
{
    int i = blockIdx.x * 256 + threadIdx.x;
    if (i < n) {
        int o = offsets[i] + bsum[blockIdx.x];
        offsets[i] = o;
        cursor[i]  = o;
        logdeg[i]  = logf((float)deg[i]);
    }
    if (i == 0) offsets[n] = E;
}

__global__ void scatter_kernel(const int* __restrict__ dst, const int* __restrict__ src,
                               const int* __restrict__ rid, int* __restrict__ cursor,
                               int* __restrict__ csr_src, int* __restrict__ csr_rid, int E)
{
    int i = blockIdx.x * blockDim.x + threadIdx.x;
    if (i < E) {
        int p = atomicAdd(&cursor[dst[i]], 1);
        csr_src[p] = src[i];
        csr_rid[p] = rid[i];
    }
}

// ---------------------------------------------------------------------------
// Head-major repacks: each head's feature slice becomes a compact [N][32]
// table (1.25 MB) that fits one XCD's L2. blockIdx%8==head pinning in the
// consumers then makes all gathers local-L2 hits.
// proj [N,768] -> fh_h/ftl_h/fen_h each [8][N][32]
// ---------------------------------------------------------------------------
__global__ __launch_bounds__(256) void repack_heads_kernel(
    const unsigned short* __restrict__ proj,
    unsigned short* __restrict__ fh, unsigned short* __restrict__ ft,
    unsigned short* __restrict__ fe, int n)
{
    int idx = blockIdx.x * 256 + threadIdx.x;   // over n * 192 chunks of 4 bf16
    if (idx >= n * 192) return;
    int node = idx / 192, c = idx - node * 192;      // c in [0,192)
    int part = c >> 6, rem = c & 63;                 // rem = h*8 + d4
    int h = rem >> 3, d4 = rem & 7;
    unsigned long long v = *(const unsigned long long*)(proj + (size_t)node * 768 + c * 4);
    unsigned short* dst = (part == 0) ? fh : (part == 1) ? ft : fe;
    *(unsigned long long*)(dst + ((size_t)h * n + node) * 32 + d4 * 4) = v;
}

// frel [100,256] -> frel_h [8][100][32]
__global__ __launch_bounds__(256) void repack_rel_kernel(
    const unsigned short* __restrict__ frel, unsigned short* __restrict__ out)
{
    int idx = blockIdx.x * 256 + threadIdx.x;   // over 100*64 chunks
    if (idx >= N_REL * 64) return;
    int r = idx >> 6, rem = idx & 63;
    int h = rem >> 3, d4 = rem & 7;
    unsigned long long v = *(const unsigned long long*)(frel + (size_t)r * FDIM + rem * 4);
    *(unsigned long long*)(out + ((size_t)h * N_REL + r) * 32 + d4 * 4) = v;
}

// ---------------------------------------------------------------------------
// Head-partitioned edge attention. Wave = one (node, head); head = blockIdx%8
// (pins each head to one XCD whose L2 holds that head's 1.25 MB fh table).
// 8 lanes per edge (8B of the 64B row each), 8 edges in flight.
// In-wave denominator (no atomics). Writes unnormalized exp into a_h[h][e]
// and 1/denom into invd_h[h][node].
// ---------------------------------------------------------------------------
__global__ __launch_bounds__(256, 8) void edge_score_h_kernel(
    const unsigned short* __restrict__ fhh,    // [8][n][32]
    const unsigned short* __restrict__ ftlh,   // [8][n][32]
    const unsigned short* __restrict__ frelh,  // [8][100][32]
    const float* __restrict__ attn,            // [8][32]
    const int* __restrict__ csr_src, const int* __restrict__ csr_rid,
    const int* __restrict__ offsets, const float* __restrict__ logdeg,
    float* __restrict__ a_h, float* __restrict__ invd_h, int n)
{
    int head = blockIdx.x & 7;
    int node = (blockIdx.x >> 3) * 4 + (threadIdx.x >> 6);
    if (node >= n) return;
    int lane = threadIdx.x & 63;
    int g = lane >> 3, li = lane & 7;
    int start = offsets[node], end = offsets[node + 1];
    float scale = logdeg[node] * (1.0f / 32.0f);

    const size_t hb = (size_t)head * n;
    const size_t rb = (size_t)head * N_REL;
    uint2 tp = *(const uint2*)(ftlh + (hb + node) * 32 + li * 4);
    float t0 = bf_lo(tp.x), t1 = bf_hi(tp.x), t2 = bf_lo(tp.y), t3 = bf_hi(tp.y);
    float4 av = *(const float4*)(attn + head * 32 + li * 4);
    float* ah = a_h + (size_t)head * N_EDGES;

    float dsum = 0.f;
    for (int p = start; p < end; p += 8) {
        int e = p + g;
        bool va = e < end;
        int ee = va ? e : end - 1;
        int s = csr_src[ee], r = csr_rid[ee];
        uint2 hp = *(const uint2*)(fhh + (hb + s) * 32 + li * 4);
        uint2 rp = *(const uint2*)(frelh + (rb + r) * 32 + li * 4);
        float m0 = bf_lo(hp.x) * t0 * bf_lo(rp.x);
        m0 = (m0 > 0.f) ? m0 : 0.2f * m0;
        float m1 = bf_hi(hp.x) * t1 * bf_hi(rp.x);
        m1 = (m1 > 0.f) ? m1 : 0.2f * m1;
        float m2 = bf_lo(hp.y) * t2 * bf_lo(rp.y);
        m2 = (m2 > 0.f) ? m2 : 0.2f * m2;
        float m3 = bf_hi(hp.y) * t3 * bf_hi(rp.y);
        m3 = (m3 > 0.f) ? m3 : 0.2f * m3;
        float sum = m0 * av.x + m1 * av.y + m2 * av.z + m3 * av.w;
        sum += __shfl_xor(sum, 1);
        sum += __shfl_xor(sum, 2);
        sum += __shfl_xor(sum, 4);
        float ex = va ? expf(sum * scale) : 0.f;
        if (va && li == 0) ah[e] = ex;
        dsum += ex;                       // identical across the 8 lanes
    }
    dsum += __shfl_xor(dsum, 8);
    dsum += __shfl_xor(dsum, 16);
    dsum += __shfl_xor(dsum, 32);
    if (lane == 0) invd_h[hb + node] = 1.0f / dsum;
}

// ---------------------------------------------------------------------------
// Head-partitioned PPR hop. Wave = one (node, head); head = blockIdx%8 pins
// the head's 1.25 MB fin table to one XCD's L2 (producer->consumer affinity
// holds across hops). 8 lanes/edge, 8 edges in flight, acc = 4 floats/lane.
// node_major!=0: write [n][256] layout (final hop feeds rst_ln).
// ---------------------------------------------------------------------------
__global__ __launch_bounds__(256, 8) void diffuse_h_kernel(
    const unsigned short* __restrict__ fin_h,    // [8][n][32]
    const unsigned short* __restrict__ feat0_h,  // [8][n][32]
    const float* __restrict__ a_h, const float* __restrict__ invd_h,
    const int* __restrict__ csr_src, const int* __restrict__ offsets,
    unsigned short* __restrict__ fout, int node_major, int n)
{
    int head = blockIdx.x & 7;
    int node = (blockIdx.x >> 3) * 4 + (threadIdx.x >> 6);
    if (node >= n) return;
    int lane = threadIdx.x & 63;
    int g = lane >> 3, li = lane & 7;
    int start = offsets[node], end = offsets[node + 1];
    const size_t hb = (size_t)head * n;
    float wn = invd_h[hb + node];
    const float* ah = a_h + (size_t)head * N_EDGES;

    float a0 = 0.f, a1 = 0.f, a2 = 0.f, a3 = 0.f;
    for (int p = start; p < end; p += 8) {
        int e = p + g;
        bool va = e < end;
        int ee = va ? e : end - 1;
        int s = csr_src[ee];
        float w = va ? ah[ee] : 0.f;
        uint2 u = *(const uint2*)(fin_h + (hb + s) * 32 + li * 4);
        a0 += w * bf_lo(u.x); a1 += w * bf_hi(u.x);
        a2 += w * bf_lo(u.y); a3 += w * bf_hi(u.y);
    }
    #pragma unroll
    for (int d = 8; d < 64; d <<= 1) {
        a0 += __shfl_xor(a0, d);
        a1 += __shfl_xor(a1, d);
        a2 += __shfl_xor(a2, d);
        a3 += __shfl_xor(a3, d);
    }
    if (g == 0) {
        uint2 f0 = *(const uint2*)(feat0_h + (hb + node) * 32 + li * 4);
        unsigned short o0 = f2bf(0.9f * a0 * wn + 0.1f * bf_lo(f0.x));
        unsigned short o1 = f2bf(0.9f * a1 * wn + 0.1f * bf_hi(f0.x));
        unsigned short o2 = f2bf(0.9f * a2 * wn + 0.1f * bf_lo(f0.y));
        unsigned short o3 = f2bf(0.9f * a3 * wn + 0.1f * bf_hi(f0.y));
        uint2 w2;
        w2.x = (unsigned int)o0 | ((unsigned int)o1 << 16);
        w2.y = (unsigned int)o2 | ((unsigned int)o3 << 16);
        if (node_major)
            *(uint2*)(fout + (size_t)node * FDIM + head * 32 + li * 4) = w2;
        else
            *(uint2*)(fout + (hb + node) * 32 + li * 4) = w2;
    }
}

// ---------------------------------------------------------------------------
extern "C" void kernel_launch(void* const* d_in, const int* in_sizes, int n_in,
                              void* d_out, int out_size, void* d_ws, size_t ws_size,
                              hipStream_t stream)
{
    const float* ent_feat = (const float*)d_in[0];
    const float* rel_feat = (const float*)d_in[1];
    const float* W_head   = (const float*)d_in[2];
    const float* W_tail   = (const float*)d_in[3];
    const float* W_ent    = (const float*)d_in[4];
    const float* W_rel    = (const float*)d_in[5];
    const float* attn     = (const float*)d_in[6];
    const float* ln_ent_g = (const float*)d_in[7];
    const float* ln_ent_b = (const float*)d_in[8];
    const float* ln_rel_g = (const float*)d_in[9];
    const float* ln_rel_b = (const float*)d_in[10];
    const float* ln_ff_g  = (const float*)d_in[11];
    const float* ln_ff_b  = (const float*)d_in[12];
    const float* W1       = (const float*)d_in[13];
    const float* b1       = (const float*)d_in[14];
    const float* W2       = (const float*)d_in[15];
    const float* b2       = (const float*)d_in[16];
    const int*   src      = (const int*)d_in[17];
    const int*   dst      = (const int*)d_in[18];
    const int*   rid      = (const int*)d_in[19];
    float* out = (float*)d_out;

    // ---- workspace carve (bytes, 256-aligned) ----
    char* base = (char*)d_ws;
    auto carve = [&](size_t bytes) { char* p = base; base += (bytes + 255) & ~(size_t)255; return p; };
    unsigned short* xb    = (unsigned short*)carve((size_t)N_NODES * FDIM * 2);
    unsigned short* projb = (unsigned short*)carve((size_t)N_NODES * 768 * 2);
    unsigned short* rlnb  = (unsigned short*)carve((size_t)N_REL * FDIM * 2);
    unsigned short* frelb = (unsigned short*)carve((size_t)N_REL * FDIM * 2);
    unsigned short* WtP   = (unsigned short*)carve((size_t)768 * FDIM * 2);
    unsigned short* WtR   = (unsigned short*)carve((size_t)FDIM * FDIM * 2);
    unsigned short* W1t   = (unsigned short*)carve((size_t)1024 * FDIM * 2);
    unsigned short* W2t   = (unsigned short*)carve((size_t)FDIM * 1024 * 2);
    unsigned short* fhh   = (unsigned short*)carve((size_t)NHEAD * N_NODES * HDIM * 2);
    unsigned short* ftlh  = (unsigned short*)carve((size_t)NHEAD * N_NODES * HDIM * 2);
    unsigned short* fenh  = (unsigned short*)carve((size_t)NHEAD * N_NODES * HDIM * 2);
    unsigned short* frelh = (unsigned short*)carve((size_t)NHEAD * N_REL * HDIM * 2);
    unsigned short* g0h   = (unsigned short*)carve((size_t)NHEAD * N_NODES * HDIM * 2);
    unsigned short* g1h   = (unsigned short*)carve((size_t)NHEAD * N_NODES * HDIM * 2);
    unsigned short* hb0   = (unsigned short*)carve((size_t)N_NODES * FDIM * 2);
    unsigned short* yb    = (unsigned short*)carve((size_t)N_NODES * FDIM * 2);
    unsigned short* t1b   = (unsigned short*)carve((size_t)N_NODES * 1024 * 2);
    float* rst     = (float*)carve((size_t)N_NODES * FDIM * 4);
    float* a_h     = (float*)carve((size_t)NHEAD * N_EDGES * 4);
    float* invd_h  = (float*)carve((size_t)NHEAD * N_NODES * 4);
    int*   csr_src = (int*)carve((size_t)(N_EDGES + 64) * 4);
    int*   csr_rid = (int*)carve((size_t)(N_EDGES + 64) * 4);
    int*   deg     = (int*)carve((size_t)N_NODES * 4);
    float* logdeg  = (float*)carve((size_t)N_NODES * 4);
    int*   offsets = (int*)carve((size_t)(N_NODES + 1) * 4);
    int*   cursor  = (int*)carve((size_t)N_NODES * 4);
    int*   bsum    = (int*)carve((size_t)SCAN_BLOCKS * 4);

    hipMemsetAsync(deg, 0, (size_t)N_NODES * 4, stream);

    // LN -> bf16
    ln_bf16_kernel<<<N_NODES, 64, 0, stream>>>(ent_feat, ln_ent_g, ln_ent_b, xb, N_NODES);
    ln_bf16_kernel<<<N_REL, 64, 0, stream>>>(rel_feat, ln_rel_g, ln_rel_b, rlnb, N_REL);

    // weight transposes (fp32 [K,N] -> bf16 [N,K]); WtP rows = [head | tail | ent]
    transpose_bf16_kernel<<<(65536 + 255) / 256, 256, 0, stream>>>(W_head, WtP,              FDIM, FDIM);
    transpose_bf16_kernel<<<(65536 + 255) / 256, 256, 0, stream>>>(W_tail, WtP + 256 * FDIM, FDIM, FDIM);
    transpose_bf16_kernel<<<(65536 + 255) / 256, 256, 0, stream>>>(W_ent,  WtP + 512 * FDIM, FDIM, FDIM);
    transpose_bf16_kernel<<<(65536 + 255) / 256, 256, 0, stream>>>(W_rel,  WtR, FDIM, FDIM);
    transpose_bf16_kernel<<<(262144 + 255) / 256, 256, 0, stream>>>(W1, W1t, FDIM, 1024);
    transpose_bf16_kernel<<<(262144 + 255) / 256, 256, 0, stream>>>(W2, W2t, 1024, FDIM);

    // fused projection GEMM: proj[N,768] = xb @ [Wh|Wt|We]  (bf16 out)
    dim3 gproj((N_NODES + 127) / 128, 768 / 128);
    mfma_gemm_bt<<<gproj, 256, 0, stream>>>(xb, WtP, nullptr, nullptr, nullptr, projb,
                                            N_NODES, FDIM, 768, 0);
    dim3 grel(1, FDIM / 128);
    mfma_gemm_bt<<<grel, 256, 0, stream>>>(rlnb, WtR, nullptr, nullptr, nullptr, frelb,
                                           N_REL, FDIM, FDIM, 0);

    // head-major repacks (1.25 MB/head tables -> per-XCD L2 residency)
    repack_heads_kernel<<<(N_NODES * 192 + 255) / 256, 256, 0, stream>>>(
        projb, fhh, ftlh, fenh, N_NODES);
    repack_rel_kernel<<<(N_REL * 64 + 255) / 256, 256, 0, stream>>>(frelb, frelh);

    // CSR build (count -> 3-phase parallel scan -> scatter)
    count_kernel<<<(N_EDGES + 255) / 256, 256, 0, stream>>>(dst, deg, N_EDGES);
    scan1_kernel<<<SCAN_BLOCKS, 256, 0, stream>>>(deg, offsets, bsum, N_NODES);
    scan2_kernel<<<1, 128, 0, stream>>>(bsum, SCAN_BLOCKS);
    scan3_kernel<<<SCAN_BLOCKS, 256, 0, stream>>>(deg, offsets, bsum, cursor, logdeg,
                                                  N_NODES, N_EDGES);
    scatter_kernel<<<(N_EDGES + 255) / 256, 256, 0, stream>>>(dst, src, rid, cursor,
                                                              csr_src, csr_rid, N_EDGES);

    // head-partitioned attention scores + in-wave softmax denominators
    int ghead = 8 * ((N_NODES + 3) / 4);
    edge_score_h_kernel<<<ghead, 256, 0, stream>>>(
        fhh, ftlh, frelh, attn, csr_src, csr_rid, offsets, logdeg, a_h, invd_h, N_NODES);

    // 5-hop PPR diffusion, head-partitioned: fenh -> g0 -> g1 -> g0 -> g1 -> hb0
    diffuse_h_kernel<<<ghead, 256, 0, stream>>>(fenh, fenh, a_h, invd_h, csr_src, offsets, g0h, 0, N_NODES);
    diffuse_h_kernel<<<ghead, 256, 0, stream>>>(g0h,  fenh, a_h, invd_h, csr_src, offsets, g1h, 0, N_NODES);
    diffuse_h_kernel<<<ghead, 256, 0, stream>>>(g1h,  fenh, a_h, invd_h, csr_src, offsets, g0h, 0, N_NODES);
    diffuse_h_kernel<<<ghead, 256, 0, stream>>>(g0h,  fenh, a_h, invd_h, csr_src, offsets, g1h, 0, N_NODES);
    diffuse_h_kernel<<<ghead, 256, 0, stream>>>(g1h,  fenh, a_h, invd_h, csr_src, offsets, hb0, 1, N_NODES);

    // residual + pre-LN
    rst_ln_kernel<<<N_NODES, 64, 0, stream>>>(hb0, ent_feat, ln_ff_g, ln_ff_b, rst, yb);

    // FFN1: t1 = relu(y@W1 + b1) [bf16], 128x128 tiles
    dim3 gff1((N_NODES + 127) / 128, 1024 / 128);
    mfma_gemm_bt<<<gff1, 256, 0, stream>>>(yb, W1t, b1, nullptr, nullptr, t1b,
                                           N_NODES, FDIM, 1024, 1);
    // FFN2: out = t1@W2 + b2 + rst, 64x128 tiles
    dim3 gff2((N_NODES + 63) / 64, FDIM / 128);
    mfma_gemm64_bt<<<gff2, 256, 0, stream>>>(t1b, W2t, b2, rst, out,
                                             N_NODES, 1024, FDIM);
}

// Round 6
// 547.125 us; speedup vs baseline: 1.2483x; 1.2483x over previous
//
#include <hip/hip_runtime.h>

#define N_NODES 20000
#define N_EDGES 320000
#define N_REL   100
#define FDIM    256
#define NHEAD   8
#define HDIM    32
#define SCAN_BLOCKS ((N_NODES + 255) / 256)   // 79

using short8 = __attribute__((ext_vector_type(8))) short;   // 8 bf16 in 4 VGPRs
using f32x4  = __attribute__((ext_vector_type(4))) float;

__device__ inline unsigned short f2bf(float f) {
    union { float f; unsigned int u; } v; v.f = f;
    unsigned int r = v.u + 0x7fff + ((v.u >> 16) & 1);   // RNE
    return (unsigned short)(r >> 16);
}
__device__ inline float bf2f(unsigned short u) {
    union { unsigned int i; float f; } v; v.i = ((unsigned int)u) << 16; return v.f;
}
__device__ inline float4 bf4(ushort4 u) {
    return make_float4(bf2f(u.x), bf2f(u.y), bf2f(u.z), bf2f(u.w));
}
__device__ inline float bf_lo(unsigned int u) {
    union { unsigned int i; float f; } v; v.i = u << 16; return v.f;
}
__device__ inline float bf_hi(unsigned int u) {
    union { unsigned int i; float f; } v; v.i = u & 0xffff0000u; return v.f;
}
// unpack 8 bf16 (uint4) -> 8 fp32
__device__ inline void unpack8(float* d, uint4 u) {
    d[0] = bf_lo(u.x); d[1] = bf_hi(u.x);
    d[2] = bf_lo(u.y); d[3] = bf_hi(u.y);
    d[4] = bf_lo(u.z); d[5] = bf_hi(u.z);
    d[6] = bf_lo(u.w); d[7] = bf_hi(u.w);
}
// acc[k] += w * bf16(u)[k], 8 elements (unpack on the fly)
__device__ inline void fma8(float* acc, uint4 u, float w) {
    acc[0] += w * bf_lo(u.x); acc[1] += w * bf_hi(u.x);
    acc[2] += w * bf_lo(u.y); acc[3] += w * bf_hi(u.y);
    acc[4] += w * bf_lo(u.z); acc[5] += w * bf_hi(u.z);
    acc[6] += w * bf_lo(u.w); acc[7] += w * bf_hi(u.w);
}
// direct global -> LDS DMA, 16 bytes per lane (gfx950 global_load_lds_dwordx4)
__device__ __forceinline__ void g2lds16(const unsigned short* g, unsigned short* l) {
    __builtin_amdgcn_global_load_lds(
        (const __attribute__((address_space(1))) unsigned int*)g,
        (__attribute__((address_space(3))) unsigned int*)l,
        16, 0, 0);
}

// bijective XCD swizzle (m204)
__device__ inline void xcd_tile(int* m0, int* n0, int tm, int tn) {
    int nwg  = gridDim.x * gridDim.y;
    int wgid = blockIdx.x + blockIdx.y * gridDim.x;
    int q = nwg >> 3, r = nwg & 7;
    int xcd = wgid & 7, pos = wgid >> 3;
    int nid = (xcd < r ? xcd * (q + 1) : r * (q + 1) + (xcd - r) * q) + pos;
    int gy = gridDim.y;
    int bx = nid / gy;
    int by = nid - bx * gy;
    *m0 = bx * tm;
    *n0 = by * tn;
}

// ---------------------------------------------------------------------------
// LayerNorm over 256 features -> bf16 output. One wave per row.
// ---------------------------------------------------------------------------
__global__ __launch_bounds__(64) void ln_bf16_kernel(
    const float* __restrict__ in, const float* __restrict__ g,
    const float* __restrict__ b, unsigned short* __restrict__ out, int rows)
{
    int row = blockIdx.x;
    if (row >= rows) return;
    int tid = threadIdx.x;
    const float4 v = *(const float4*)(in + (size_t)row * FDIM + tid * 4);
    float s = v.x + v.y + v.z + v.w;
    float q = v.x * v.x + v.y * v.y + v.z * v.z + v.w * v.w;
    #pragma unroll
    for (int d = 1; d < 64; d <<= 1) { s += __shfl_xor(s, d); q += __shfl_xor(q, d); }
    float mean = s * (1.0f / FDIM);
    float var  = q * (1.0f / FDIM) - mean * mean;
    float inv  = rsqrtf(var + 1e-5f);
    float4 gg = *(const float4*)(g + tid * 4);
    float4 bb = *(const float4*)(b + tid * 4);
    ushort4 o;
    o.x = f2bf((v.x - mean) * inv * gg.x + bb.x);
    o.y = f2bf((v.y - mean) * inv * gg.y + bb.y);
    o.z = f2bf((v.z - mean) * inv * gg.z + bb.z);
    o.w = f2bf((v.w - mean) * inv * gg.w + bb.w);
    *(ushort4*)(out + (size_t)row * FDIM + tid * 4) = o;
}

// rst = bf2f(feat) + ent (fp32) ; y = LN(rst) (bf16)
__global__ __launch_bounds__(64) void rst_ln_kernel(
    const unsigned short* __restrict__ feat, const float* __restrict__ ent,
    const float* __restrict__ g, const float* __restrict__ b,
    float* __restrict__ rst, unsigned short* __restrict__ y)
{
    int row = blockIdx.x;
    int tid = threadIdx.x;
    const float4 f = bf4(*(const ushort4*)(feat + (size_t)row * FDIM + tid * 4));
    const float4 e = *(const float4*)(ent + (size_t)row * FDIM + tid * 4);
    float4 r;
    r.x = f.x + e.x; r.y = f.y + e.y; r.z = f.z + e.z; r.w = f.w + e.w;
    *(float4*)(rst + (size_t)row * FDIM + tid * 4) = r;
    float s = r.x + r.y + r.z + r.w;
    float q = r.x * r.x + r.y * r.y + r.z * r.z + r.w * r.w;
    #pragma unroll
    for (int d = 1; d < 64; d <<= 1) { s += __shfl_xor(s, d); q += __shfl_xor(q, d); }
    float mean = s * (1.0f / FDIM);
    float var  = q * (1.0f / FDIM) - mean * mean;
    float inv  = rsqrtf(var + 1e-5f);
    float4 gg = *(const float4*)(g + tid * 4);
    float4 bb = *(const float4*)(b + tid * 4);
    ushort4 o;
    o.x = f2bf((r.x - mean) * inv * gg.x + bb.x);
    o.y = f2bf((r.y - mean) * inv * gg.y + bb.y);
    o.z = f2bf((r.z - mean) * inv * gg.z + bb.z);
    o.w = f2bf((r.w - mean) * inv * gg.w + bb.w);
    *(ushort4*)(y + (size_t)row * FDIM + tid * 4) = o;
}

// Wt[n*K + k] = bf16(W[k*N + n])
__global__ void transpose_bf16_kernel(const float* __restrict__ W,
                                      unsigned short* __restrict__ Wt, int K, int N)
{
    int idx = blockIdx.x * 256 + threadIdx.x;
    if (idx >= K * N) return;
    int n = idx / K, k = idx - n * K;
    Wt[idx] = f2bf(W[(size_t)k * N + n]);
}

// ---------------------------------------------------------------------------
// bf16 MFMA GEMM (B^T): C[M,N] = A[M,K] @ Bt[N,K]^T  (+bias)(relu)(+add)
// 128x128 tile, 4 waves, 4x4 16x16x32 frags/wave, BK=32.
// Double-buffered LDS + single barrier per K-step + XCD-aware swizzle.
// ---------------------------------------------------------------------------
__global__ __launch_bounds__(256) void mfma_gemm_bt(
    const unsigned short* __restrict__ A, const unsigned short* __restrict__ Bt,
    const float* __restrict__ bias, const float* __restrict__ add,
    float* __restrict__ Cf, unsigned short* __restrict__ Cb,
    int M, int K, int N, int relu)
{
    __shared__ unsigned short As[2][128 * 32];
    __shared__ unsigned short Bs[2][128 * 32];
    int tid  = threadIdx.x;
    int wave = tid >> 6, lane = tid & 63;
    int quad = lane >> 4, l16 = lane & 15;
    int m0, n0;
    xcd_tile(&m0, &n0, 128, 128);
    int wr = (wave >> 1) * 64, wc = (wave & 1) * 64;

    f32x4 acc[4][4] = {};

    int cA = tid, cB = tid + 256;
    int rA0 = cA >> 2, kA0 = (cA & 3) * 8;
    int rB0 = cB >> 2, kB0 = (cB & 3) * 8;
    int rA = m0 + rA0; if (rA >= M) rA = M - 1;
    int rB = m0 + rB0; if (rB >= M) rB = M - 1;
    const unsigned short* gA0 = A + (size_t)rA * K + kA0;
    const unsigned short* gA1 = A + (size_t)rB * K + kB0;
    const unsigned short* gB0 = Bt + (size_t)(n0 + rA0) * K + kA0;
    const unsigned short* gB1 = Bt + (size_t)(n0 + rB0) * K + kB0;

    g2lds16(gA0, As[0] + cA * 8);
    g2lds16(gA1, As[0] + cB * 8);
    g2lds16(gB0, Bs[0] + cA * 8);
    g2lds16(gB1, Bs[0] + cB * 8);
    __syncthreads();

    int cur = 0;
    for (int k0 = 0; k0 < K; k0 += 32) {
        int k1 = k0 + 32;
        if (k1 < K) {
            int nb = cur ^ 1;
            g2lds16(gA0 + k1, As[nb] + cA * 8);
            g2lds16(gA1 + k1, As[nb] + cB * 8);
            g2lds16(gB0 + k1, Bs[nb] + cA * 8);
            g2lds16(gB1 + k1, Bs[nb] + cB * 8);
        }
        short8 af[4], bfr[4];
        #pragma unroll
        for (int i = 0; i < 4; ++i)
            af[i] = *(const short8*)(As[cur] + (wr + i * 16 + l16) * 32 + quad * 8);
        #pragma unroll
        for (int j = 0; j < 4; ++j)
            bfr[j] = *(const short8*)(Bs[cur] + (wc + j * 16 + l16) * 32 + quad * 8);
        #pragma unroll
        for (int i = 0; i < 4; ++i)
            #pragma unroll
            for (int j = 0; j < 4; ++j)
                acc[i][j] = __builtin_amdgcn_mfma_f32_16x16x32_bf16(
                    af[i], bfr[j], acc[i][j], 0, 0, 0);
        __syncthreads();
        cur ^= 1;
    }

    #pragma unroll
    for (int i = 0; i < 4; ++i) {
        #pragma unroll
        for (int j = 0; j < 4; ++j) {
            int col = n0 + wc + j * 16 + l16;
            float bsv = bias ? bias[col] : 0.0f;
            #pragma unroll
            for (int r = 0; r < 4; ++r) {
                int row = m0 + wr + i * 16 + quad * 4 + r;
                if (row < M) {
                    float v = acc[i][j][r] + bsv;
                    if (relu) v = fmaxf(v, 0.0f);
                    if (add)  v += add[(size_t)row * N + col];
                    if (Cf) Cf[(size_t)row * N + col] = v;
                    else    Cb[(size_t)row * N + col] = f2bf(v);
                }
            }
        }
    }
}

// ---------------------------------------------------------------------------
// 64x128-tile variant (small grids / long K, e.g. FFN2): 4 waves, 4x2 frags.
// ---------------------------------------------------------------------------
__global__ __launch_bounds__(256) void mfma_gemm64_bt(
    const unsigned short* __restrict__ A, const unsigned short* __restrict__ Bt,
    const float* __restrict__ bias, const float* __restrict__ add,
    float* __restrict__ Cf, int M, int K, int N)
{
    __shared__ unsigned short As[2][64 * 32];
    __shared__ unsigned short Bs[2][128 * 32];
    int tid  = threadIdx.x;
    int wave = tid >> 6, lane = tid & 63;
    int quad = lane >> 4, l16 = lane & 15;
    int m0, n0;
    xcd_tile(&m0, &n0, 64, 128);
    int wc = wave * 32;

    f32x4 acc[4][2] = {};

    int rA0 = tid >> 2, kA0 = (tid & 3) * 8;
    int cB0 = tid, cB1 = tid + 256;
    int rB0 = cB0 >> 2, kB0 = (cB0 & 3) * 8;
    int rB1 = cB1 >> 2, kB1 = (cB1 & 3) * 8;
    int rA = m0 + rA0; if (rA >= M) rA = M - 1;
    const unsigned short* gA  = A + (size_t)rA * K + kA0;
    const unsigned short* gB0 = Bt + (size_t)(n0 + rB0) * K + kB0;
    const unsigned short* gB1 = Bt + (size_t)(n0 + rB1) * K + kB1;

    g2lds16(gA,  As[0] + tid * 8);
    g2lds16(gB0, Bs[0] + cB0 * 8);
    g2lds16(gB1, Bs[0] + cB1 * 8);
    __syncthreads();

    int cur = 0;
    for (int k0 = 0; k0 < K; k0 += 32) {
        int k1 = k0 + 32;
        if (k1 < K) {
            int nb = cur ^ 1;
            g2lds16(gA + k1,  As[nb] + tid * 8);
            g2lds16(gB0 + k1, Bs[nb] + cB0 * 8);
            g2lds16(gB1 + k1, Bs[nb] + cB1 * 8);
        }
        short8 af[4], bfr[2];
        #pragma unroll
        for (int i = 0; i < 4; ++i)
            af[i] = *(const short8*)(As[cur] + (i * 16 + l16) * 32 + quad * 8);
        #pragma unroll
        for (int j = 0; j < 2; ++j)
            bfr[j] = *(const short8*)(Bs[cur] + (wc + j * 16 + l16) * 32 + quad * 8);
        #pragma unroll
        for (int i = 0; i < 4; ++i)
            #pragma unroll
            for (int j = 0; j < 2; ++j)
                acc[i][j] = __builtin_amdgcn_mfma_f32_16x16x32_bf16(
                    af[i], bfr[j], acc[i][j], 0, 0, 0);
        __syncthreads();
        cur ^= 1;
    }

    #pragma unroll
    for (int i = 0; i < 4; ++i) {
        #pragma unroll
        for (int j = 0; j < 2; ++j) {
            int col = n0 + wc + j * 16 + l16;
            float bsv = bias ? bias[col] : 0.0f;
            #pragma unroll
            for (int r = 0; r < 4; ++r) {
                int row = m0 + i * 16 + quad * 4 + r;
                if (row < M) {
                    float v = acc[i][j][r] + bsv;
                    if (add) v += add[(size_t)row * N + col];
                    Cf[(size_t)row * N + col] = v;
                }
            }
        }
    }
}

// ---------------------------------------------------------------------------
// Graph plumbing: degree count -> 3-phase parallel scan -> scatter
// ---------------------------------------------------------------------------
__global__ void count_kernel(const int* __restrict__ dst, int* __restrict__ deg, int E)
{
    int i = blockIdx.x * blockDim.x + threadIdx.x;
    if (i < E) atomicAdd(&deg[dst[i]], 1);
}

__global__ __launch_bounds__(256) void scan1_kernel(
    const int* __restrict__ deg, int* __restrict__ offsets, int* __restrict__ bsum, int n)
{
    __shared__ int tmp[256];
    int tid = threadIdx.x;
    int i = blockIdx.x * 256 + tid;
    int v = (i < n) ? deg[i] : 0;
    tmp[tid] = v;
    __syncthreads();
    for (int d = 1; d < 256; d <<= 1) {
        int u = (tid >= d) ? tmp[tid - d] : 0;
        __syncthreads();
        tmp[tid] += u;
        __syncthreads();
    }
    if (i < n) offsets[i] = tmp[tid] - v;
    if (tid == 255) bsum[blockIdx.x] = tmp[255];
}

__global__ __launch_bounds__(128) void scan2_kernel(int* __restrict__ bsum, int nb)
{
    __shared__ int tmp[128];
    int tid = threadIdx.x;
    int v = (tid < nb) ? bsum[tid] : 0;
    tmp[tid] = v;
    __syncthreads();
    for (int d = 1; d < 128; d <<= 1) {
        int u = (tid >= d) ? tmp[tid - d] : 0;
        __syncthreads();
        tmp[tid] += u;
        __syncthreads();
    }
    if (tid < nb) bsum[tid] = tmp[tid] - v;
}

__global__ __launch_bounds__(256) void scan3_kernel(
    const int* __restrict__ deg, int* __restrict__ offsets,
    const int* __restrict__ bsum, int* __restrict__ cursor,
    float* __restrict__ logdeg, int n, int E)
{
    int i = blockIdx.x * 256 + threadIdx.x;
    if (i < n) {
        int o = offsets[i] + bsum[blockIdx.x];
        offsets[i] = o;
        cursor[i]  = o;
        logdeg[i]  = logf((float)deg[i]);
    }
    if (i == 0) offsets[n] = E;
}

__global__ void scatter_kernel(const int* __restrict__ dst, const int* __restrict__ src,
                               const int* __restrict__ rid, int* __restrict__ cursor,
                               int* __restrict__ csr_src, int* __restrict__ csr_rid, int E)
{
    int i = blockIdx.x * blockDim.x + threadIdx.x;
    if (i < E) {
        int p = atomicAdd(&cursor[dst[i]], 1);
        csr_src[p] = src[i];
        csr_rid[p] = rid[i];
    }
}

// ---------------------------------------------------------------------------
// Head-PAIR-major repacks. Pair p = heads (2p,2p+1) = features [p*64,p*64+64).
// Each pair table [N][64] = 2.5 MB -> fits one XCD's 4 MB L2; consumers pin
// pair p to XCDs {p, p+4} via blockIdx&7, so gathers become local-L2 hits
// at full uint4 width (r4 lesson: locality AND 16B loads, not either/or).
// proj [N,768] -> fh_p/ftl_p/fen_p each [4][N][64]
// FIX (r5 bug): a 768-feat row is 96 uint4 chunks, not 48 — pairs 2,3 were
// never repacked (absmax 0.64). part = c>>5, w = c&31 now cover all 256.
// ---------------------------------------------------------------------------
__global__ __launch_bounds__(256) void repack_pair_kernel(
    const unsigned short* __restrict__ proj,
    unsigned short* __restrict__ fh, unsigned short* __restrict__ ft,
    unsigned short* __restrict__ fe, int n)
{
    int idx = blockIdx.x * 256 + threadIdx.x;    // over n*96 uint4 (16B) chunks
    if (idx >= n * 96) return;
    int node = idx / 96, c = idx - node * 96;    // c in [0,96)
    int part = c >> 5, w = c & 31;               // w = pair*8 + cc, 32/part
    int pair = w >> 3, cc = w & 7;
    uint4 v = *(const uint4*)(proj + (size_t)node * 768 + part * 256 + w * 8);
    unsigned short* dst = (part == 0) ? fh : (part == 1) ? ft : fe;
    *(uint4*)(dst + ((size_t)pair * n + node) * 64 + cc * 8) = v;
}

// frel [100,256] -> frel_p [4][100][64]
__global__ __launch_bounds__(256) void repack_rel_pair_kernel(
    const unsigned short* __restrict__ frel, unsigned short* __restrict__ out)
{
    int idx = blockIdx.x * 256 + threadIdx.x;    // over 100*32 uint4 chunks
    if (idx >= N_REL * 32) return;
    int r = idx >> 5, w = idx & 31;
    int pair = w >> 3, cc = w & 7;
    uint4 v = *(const uint4*)(frel + (size_t)r * FDIM + w * 8);
    *(uint4*)(out + ((size_t)pair * N_REL + r) * 64 + cc * 8) = v;
}

// ---------------------------------------------------------------------------
// Head-pair-partitioned edge attention. Wave = (node, pair); blockIdx&7 pins
// pair p to XCDs {p,p+4} (each caches the pair's 2.5 MB tables). 8 lanes per
// edge (uint4 = 8 feats each; lanes 0-3 = head 2p, 4-7 = head 2p+1), 8 edges
// in flight. In-wave softmax denominator (no atomics). Writes unnormalized
// exp into a_p[p][e][half] and 1/denom into invd_p[p][node][half].
// ---------------------------------------------------------------------------
__global__ __launch_bounds__(256, 8) void edge_score_p_kernel(
    const unsigned short* __restrict__ fh_p,    // [4][n][64]
    const unsigned short* __restrict__ ftl_p,   // [4][n][64]
    const unsigned short* __restrict__ frel_p,  // [4][100][64]
    const float* __restrict__ attn,             // [8][32]
    const int* __restrict__ csr_src, const int* __restrict__ csr_rid,
    const int* __restrict__ offsets, const float* __restrict__ logdeg,
    float* __restrict__ a_p, float* __restrict__ invd_p, int n)
{
    int b = blockIdx.x;
    int pair = b & 3;
    int replica = (b >> 2) & 1;
    int node = (b >> 3) * 8 + replica * 4 + (threadIdx.x >> 6);
    if (node >= n) return;
    int lane = threadIdx.x & 63;
    int g = lane >> 3, li = lane & 7;
    int half = li >> 2;
    int start = offsets[node], end = offsets[node + 1];
    float scale = logdeg[node] * (1.0f / 32.0f);

    const size_t tb = (size_t)pair * n;
    uint4 tq = *(const uint4*)(ftl_p + (tb + node) * 64 + li * 8);
    float tv[8]; unpack8(tv, tq);
    const float* ab = attn + (pair * 2 + half) * 32 + (li & 3) * 8;
    float av[8];
    { float4 a0 = *(const float4*)ab, a1 = *(const float4*)(ab + 4);
      av[0] = a0.x; av[1] = a0.y; av[2] = a0.z; av[3] = a0.w;
      av[4] = a1.x; av[5] = a1.y; av[6] = a1.z; av[7] = a1.w; }

    float* ap = a_p + (size_t)pair * N_EDGES * 2;
    float dsum = 0.f;
    for (int p = start; p < end; p += 8) {
        int e = p + g;
        bool va = e < end;
        int ee = va ? e : end - 1;
        int s = csr_src[ee], r = csr_rid[ee];
        uint4 hq = *(const uint4*)(fh_p + (tb + s) * 64 + li * 8);
        uint4 rq = *(const uint4*)(frel_p + ((size_t)pair * N_REL + r) * 64 + li * 8);
        float hv[8], rv[8];
        unpack8(hv, hq); unpack8(rv, rq);
        float sum = 0.f;
        #pragma unroll
        for (int k = 0; k < 8; ++k) {
            float m = hv[k] * tv[k] * rv[k];
            m = (m > 0.f) ? m : 0.2f * m;
            sum += m * av[k];
        }
        sum += __shfl_xor(sum, 1);
        sum += __shfl_xor(sum, 2);       // 4-lane half holds its head's score
        float ex = va ? expf(sum * scale) : 0.f;
        if (va && (li & 3) == 0) ap[(size_t)e * 2 + half] = ex;
        dsum += ex;
    }
    dsum += __shfl_xor(dsum, 8);
    dsum += __shfl_xor(dsum, 16);
    dsum += __shfl_xor(dsum, 32);        // per-lane: denom of its head
    if (g == 0 && (li & 3) == 0)
        invd_p[(tb + node) * 2 + half] = 1.0f / dsum;
}

// ---------------------------------------------------------------------------
// Head-pair-partitioned PPR hop. Same decomposition/pinning as edge_score_p.
// 8 lanes/edge (uint4), 8 edges in flight, acc[8]/lane, group-reduce at end.
// node_major!=0: final hop writes [n][256] (feeds rst_ln/FFN).
// ---------------------------------------------------------------------------
__global__ __launch_bounds__(256, 8) void diffuse_p_kernel(
    const unsigned short* __restrict__ fin_p,    // [4][n][64]
    const unsigned short* __restrict__ feat0_p,  // [4][n][64] (fen)
    const float* __restrict__ a_p, const float* __restrict__ invd_p,
    const int* __restrict__ csr_src, const int* __restrict__ offsets,
    unsigned short* __restrict__ fout, int node_major, int n)
{
    int b = blockIdx.x;
    int pair = b & 3;
    int replica = (b >> 2) & 1;
    int node = (b >> 3) * 8 + replica * 4 + (threadIdx.x >> 6);
    if (node >= n) return;
    int lane = threadIdx.x & 63;
    int g = lane >> 3, li = lane & 7;
    int half = li >> 2;
    int start = offsets[node], end = offsets[node + 1];
    const size_t tb = (size_t)pair * n;
    const float* ap = a_p + (size_t)pair * N_EDGES * 2;

    float acc[8] = {};
    for (int p = start; p < end; p += 8) {
        int e = p + g;
        bool va = e < end;
        int ee = va ? e : end - 1;
        int s = csr_src[ee];
        float w = va ? ap[(size_t)ee * 2 + half] : 0.f;
        uint4 u = *(const uint4*)(fin_p + (tb + s) * 64 + li * 8);
        fma8(acc, u, w);
    }
    #pragma unroll
    for (int k = 0; k < 8; ++k) {
        acc[k] += __shfl_xor(acc[k], 8);
        acc[k] += __shfl_xor(acc[k], 16);
        acc[k] += __shfl_xor(acc[k], 32);
    }
    if (g == 0) {
        float wn = invd_p[(tb + node) * 2 + half];
        uint4 f0 = *(const uint4*)(feat0_p + (tb + node) * 64 + li * 8);
        float fv[8]; unpack8(fv, f0);
        unsigned short o[8];
        #pragma unroll
        for (int k = 0; k < 8; ++k)
            o[k] = f2bf(0.9f * acc[k] * wn + 0.1f * fv[k]);
        unsigned short* dst = node_major
            ? fout + (size_t)node * FDIM + pair * 64 + li * 8
            : fout + (tb + node) * 64 + li * 8;
        *(uint4*)dst = *(uint4*)o;
    }
}

// ---------------------------------------------------------------------------
extern "C" void kernel_launch(void* const* d_in, const int* in_sizes, int n_in,
                              void* d_out, int out_size, void* d_ws, size_t ws_size,
                              hipStream_t stream)
{
    const float* ent_feat = (const float*)d_in[0];
    const float* rel_feat = (const float*)d_in[1];
    const float* W_head   = (const float*)d_in[2];
    const float* W_tail   = (const float*)d_in[3];
    const float* W_ent    = (const float*)d_in[4];
    const float* W_rel    = (const float*)d_in[5];
    const float* attn     = (const float*)d_in[6];
    const float* ln_ent_g = (const float*)d_in[7];
    const float* ln_ent_b = (const float*)d_in[8];
    const float* ln_rel_g = (const float*)d_in[9];
    const float* ln_rel_b = (const float*)d_in[10];
    const float* ln_ff_g  = (const float*)d_in[11];
    const float* ln_ff_b  = (const float*)d_in[12];
    const float* W1       = (const float*)d_in[13];
    const float* b1       = (const float*)d_in[14];
    const float* W2       = (const float*)d_in[15];
    const float* b2       = (const float*)d_in[16];
    const int*   src      = (const int*)d_in[17];
    const int*   dst      = (const int*)d_in[18];
    const int*   rid      = (const int*)d_in[19];
    float* out = (float*)d_out;

    // ---- workspace carve (bytes, 256-aligned) ----
    char* base = (char*)d_ws;
    auto carve = [&](size_t bytes) { char* p = base; base += (bytes + 255) & ~(size_t)255; return p; };
    unsigned short* xb    = (unsigned short*)carve((size_t)N_NODES * FDIM * 2);
    unsigned short* projb = (unsigned short*)carve((size_t)N_NODES * 768 * 2);
    unsigned short* rlnb  = (unsigned short*)carve((size_t)N_REL * FDIM * 2);
    unsigned short* frelb = (unsigned short*)carve((size_t)N_REL * FDIM * 2);
    unsigned short* WtP   = (unsigned short*)carve((size_t)768 * FDIM * 2);
    unsigned short* WtR   = (unsigned short*)carve((size_t)FDIM * FDIM * 2);
    unsigned short* W1t   = (unsigned short*)carve((size_t)1024 * FDIM * 2);
    unsigned short* W2t   = (unsigned short*)carve((size_t)FDIM * 1024 * 2);
    unsigned short* fh_p  = (unsigned short*)carve((size_t)N_NODES * FDIM * 2);
    unsigned short* ftl_p = (unsigned short*)carve((size_t)N_NODES * FDIM * 2);
    unsigned short* fen_p = (unsigned short*)carve((size_t)N_NODES * FDIM * 2);
    unsigned short* frl_p = (unsigned short*)carve((size_t)N_REL * FDIM * 2);
    unsigned short* g0p   = (unsigned short*)carve((size_t)N_NODES * FDIM * 2);
    unsigned short* g1p   = (unsigned short*)carve((size_t)N_NODES * FDIM * 2);
    unsigned short* hb0   = (unsigned short*)carve((size_t)N_NODES * FDIM * 2);
    unsigned short* yb    = (unsigned short*)carve((size_t)N_NODES * FDIM * 2);
    unsigned short* t1b   = (unsigned short*)carve((size_t)N_NODES * 1024 * 2);
    float* rst     = (float*)carve((size_t)N_NODES * FDIM * 4);
    float* a_p     = (float*)carve((size_t)4 * N_EDGES * 2 * 4);
    float* invd_p  = (float*)carve((size_t)4 * N_NODES * 2 * 4);
    int*   csr_src = (int*)carve((size_t)(N_EDGES + 64) * 4);
    int*   csr_rid = (int*)carve((size_t)(N_EDGES + 64) * 4);
    int*   deg     = (int*)carve((size_t)N_NODES * 4);
    float* logdeg  = (float*)carve((size_t)N_NODES * 4);
    int*   offsets = (int*)carve((size_t)(N_NODES + 1) * 4);
    int*   cursor  = (int*)carve((size_t)N_NODES * 4);
    int*   bsum    = (int*)carve((size_t)SCAN_BLOCKS * 4);

    hipMemsetAsync(deg, 0, (size_t)N_NODES * 4, stream);

    // LN -> bf16
    ln_bf16_kernel<<<N_NODES, 64, 0, stream>>>(ent_feat, ln_ent_g, ln_ent_b, xb, N_NODES);
    ln_bf16_kernel<<<N_REL, 64, 0, stream>>>(rel_feat, ln_rel_g, ln_rel_b, rlnb, N_REL);

    // weight transposes (fp32 [K,N] -> bf16 [N,K]); WtP rows = [head | tail | ent]
    transpose_bf16_kernel<<<(65536 + 255) / 256, 256, 0, stream>>>(W_head, WtP,              FDIM, FDIM);
    transpose_bf16_kernel<<<(65536 + 255) / 256, 256, 0, stream>>>(W_tail, WtP + 256 * FDIM, FDIM, FDIM);
    transpose_bf16_kernel<<<(65536 + 255) / 256, 256, 0, stream>>>(W_ent,  WtP + 512 * FDIM, FDIM, FDIM);
    transpose_bf16_kernel<<<(65536 + 255) / 256, 256, 0, stream>>>(W_rel,  WtR, FDIM, FDIM);
    transpose_bf16_kernel<<<(262144 + 255) / 256, 256, 0, stream>>>(W1, W1t, FDIM, 1024);
    transpose_bf16_kernel<<<(262144 + 255) / 256, 256, 0, stream>>>(W2, W2t, 1024, FDIM);

    // fused projection GEMM: proj[N,768] = xb @ [Wh|Wt|We]  (bf16 out)
    dim3 gproj((N_NODES + 127) / 128, 768 / 128);
    mfma_gemm_bt<<<gproj, 256, 0, stream>>>(xb, WtP, nullptr, nullptr, nullptr, projb,
                                            N_NODES, FDIM, 768, 0);
    dim3 grel(1, FDIM / 128);
    mfma_gemm_bt<<<grel, 256, 0, stream>>>(rlnb, WtR, nullptr, nullptr, nullptr, frelb,
                                           N_REL, FDIM, FDIM, 0);

    // head-pair-major repacks (2.5 MB/pair tables -> XCD-L2 residency)
    repack_pair_kernel<<<(N_NODES * 96 + 255) / 256, 256, 0, stream>>>(
        projb, fh_p, ftl_p, fen_p, N_NODES);
    repack_rel_pair_kernel<<<(N_REL * 32 + 255) / 256, 256, 0, stream>>>(frelb, frl_p);

    // CSR build (count -> 3-phase parallel scan -> scatter)
    count_kernel<<<(N_EDGES + 255) / 256, 256, 0, stream>>>(dst, deg, N_EDGES);
    scan1_kernel<<<SCAN_BLOCKS, 256, 0, stream>>>(deg, offsets, bsum, N_NODES);
    scan2_kernel<<<1, 128, 0, stream>>>(bsum, SCAN_BLOCKS);
    scan3_kernel<<<SCAN_BLOCKS, 256, 0, stream>>>(deg, offsets, bsum, cursor, logdeg,
                                                  N_NODES, N_EDGES);
    scatter_kernel<<<(N_EDGES + 255) / 256, 256, 0, stream>>>(dst, src, rid, cursor,
                                                              csr_src, csr_rid, N_EDGES);

    // pair-partitioned attention scores + in-wave softmax denominators
    int gpair = 8 * ((N_NODES + 7) / 8);     // blockIdx&7 -> XCD; &3 -> pair
    edge_score_p_kernel<<<gpair, 256, 0, stream>>>(
        fh_p, ftl_p, frl_p, attn, csr_src, csr_rid, offsets, logdeg,
        a_p, invd_p, N_NODES);

    // 5-hop PPR diffusion, pair-partitioned: fen_p -> g0 -> g1 -> g0 -> g1 -> hb0
    diffuse_p_kernel<<<gpair, 256, 0, stream>>>(fen_p, fen_p, a_p, invd_p, csr_src, offsets, g0p, 0, N_NODES);
    diffuse_p_kernel<<<gpair, 256, 0, stream>>>(g0p,   fen_p, a_p, invd_p, csr_src, offsets, g1p, 0, N_NODES);
    diffuse_p_kernel<<<gpair, 256, 0, stream>>>(g1p,   fen_p, a_p, invd_p, csr_src, offsets, g0p, 0, N_NODES);
    diffuse_p_kernel<<<gpair, 256, 0, stream>>>(g0p,   fen_p, a_p, invd_p, csr_src, offsets, g1p, 0, N_NODES);
    diffuse_p_kernel<<<gpair, 256, 0, stream>>>(g1p,   fen_p, a_p, invd_p, csr_src, offsets, hb0, 1, N_NODES);

    // residual + pre-LN
    rst_ln_kernel<<<N_NODES, 64, 0, stream>>>(hb0, ent_feat, ln_ff_g, ln_ff_b, rst, yb);

    // FFN1: t1 = relu(y@W1 + b1) [bf16], 128x128 tiles
    dim3 gff1((N_NODES + 127) / 128, 1024 / 128);
    mfma_gemm_bt<<<gff1, 256, 0, stream>>>(yb, W1t, b1, nullptr, nullptr, t1b,
                                           N_NODES, FDIM, 1024, 1);
    // FFN2: out = t1@W2 + b2 + rst, 64x128 tiles
    dim3 gff2((N_NODES + 63) / 64, FDIM / 128);
    mfma_gemm64_bt<<<gff2, 256, 0, stream>>>(t1b, W2t, b2, rst, out,
                                             N_NODES, 1024, FDIM);
}

// Round 7
// 469.672 us; speedup vs baseline: 1.4541x; 1.1649x over previous
//
#include <hip/hip_runtime.h>

#define N_NODES 20000
#define N_EDGES 320000
#define N_REL   100
#define FDIM    256
#define NHEAD   8
#define HDIM    32
#define SCAN_BLOCKS ((N_NODES + 255) / 256)   // 79

using short8 = __attribute__((ext_vector_type(8))) short;   // 8 bf16 in 4 VGPRs
using f32x4  = __attribute__((ext_vector_type(4))) float;

__device__ inline unsigned short f2bf(float f) {
    union { float f; unsigned int u; } v; v.f = f;
    unsigned int r = v.u + 0x7fff + ((v.u >> 16) & 1);   // RNE
    return (unsigned short)(r >> 16);
}
__device__ inline float bf2f(unsigned short u) {
    union { unsigned int i; float f; } v; v.i = ((unsigned int)u) << 16; return v.f;
}
__device__ inline float4 bf4(ushort4 u) {
    return make_float4(bf2f(u.x), bf2f(u.y), bf2f(u.z), bf2f(u.w));
}
// unpack 8 bf16 (uint4) -> 8 fp32
__device__ inline void unpack8(float* d, uint4 u) {
    union { unsigned int u; float f; } t;
    t.u = u.x << 16;         d[0] = t.f;
    t.u = u.x & 0xffff0000u; d[1] = t.f;
    t.u = u.y << 16;         d[2] = t.f;
    t.u = u.y & 0xffff0000u; d[3] = t.f;
    t.u = u.z << 16;         d[4] = t.f;
    t.u = u.z & 0xffff0000u; d[5] = t.f;
    t.u = u.w << 16;         d[6] = t.f;
    t.u = u.w & 0xffff0000u; d[7] = t.f;
}
// acc[k] += w * bf16(u)[k], 8 elements
__device__ inline void fma8(float* acc, uint4 u, float w) {
    union { unsigned int u; float f; } t;
    t.u = u.x << 16;         acc[0] += w * t.f;
    t.u = u.x & 0xffff0000u; acc[1] += w * t.f;
    t.u = u.y << 16;         acc[2] += w * t.f;
    t.u = u.y & 0xffff0000u; acc[3] += w * t.f;
    t.u = u.z << 16;         acc[4] += w * t.f;
    t.u = u.z & 0xffff0000u; acc[5] += w * t.f;
    t.u = u.w << 16;         acc[6] += w * t.f;
    t.u = u.w & 0xffff0000u; acc[7] += w * t.f;
}
// direct global -> LDS DMA, 16 bytes per lane (gfx950 global_load_lds_dwordx4)
__device__ __forceinline__ void g2lds16(const unsigned short* g, unsigned short* l) {
    __builtin_amdgcn_global_load_lds(
        (const __attribute__((address_space(1))) unsigned int*)g,
        (__attribute__((address_space(3))) unsigned int*)l,
        16, 0, 0);
}

// bijective XCD swizzle (m204)
__device__ inline void xcd_tile(int* m0, int* n0, int tm, int tn) {
    int nwg  = gridDim.x * gridDim.y;
    int wgid = blockIdx.x + blockIdx.y * gridDim.x;
    int q = nwg >> 3, r = nwg & 7;
    int xcd = wgid & 7, pos = wgid >> 3;
    int nid = (xcd < r ? xcd * (q + 1) : r * (q + 1) + (xcd - r) * q) + pos;
    int gy = gridDim.y;
    int bx = nid / gy;
    int by = nid - bx * gy;
    *m0 = bx * tm;
    *n0 = by * tn;
}

// ---------------------------------------------------------------------------
// Fused LayerNorm (node rows + rel rows in one grid) -> bf16. One wave/row.
// ---------------------------------------------------------------------------
__global__ __launch_bounds__(64) void ln_fused_kernel(
    const float* __restrict__ ent, const float* __restrict__ rel,
    const float* __restrict__ ge, const float* __restrict__ be,
    const float* __restrict__ gr, const float* __restrict__ br,
    unsigned short* __restrict__ xb, unsigned short* __restrict__ rlnb)
{
    int row = blockIdx.x;
    const float *in, *g, *b; unsigned short* out; int r;
    if (row < N_NODES) { in = ent; g = ge; b = be; out = xb;   r = row; }
    else               { in = rel; g = gr; b = br; out = rlnb; r = row - N_NODES; }
    int tid = threadIdx.x;
    const float4 v = *(const float4*)(in + (size_t)r * FDIM + tid * 4);
    float s = v.x + v.y + v.z + v.w;
    float q = v.x * v.x + v.y * v.y + v.z * v.z + v.w * v.w;
    #pragma unroll
    for (int d = 1; d < 64; d <<= 1) { s += __shfl_xor(s, d); q += __shfl_xor(q, d); }
    float mean = s * (1.0f / FDIM);
    float var  = q * (1.0f / FDIM) - mean * mean;
    float inv  = rsqrtf(var + 1e-5f);
    float4 gg = *(const float4*)(g + tid * 4);
    float4 bb = *(const float4*)(b + tid * 4);
    ushort4 o;
    o.x = f2bf((v.x - mean) * inv * gg.x + bb.x);
    o.y = f2bf((v.y - mean) * inv * gg.y + bb.y);
    o.z = f2bf((v.z - mean) * inv * gg.z + bb.z);
    o.w = f2bf((v.w - mean) * inv * gg.w + bb.w);
    *(ushort4*)(out + (size_t)r * FDIM + tid * 4) = o;
}

// rst = bf2f(feat) + ent (fp32) ; y = LN(rst) (bf16)
__global__ __launch_bounds__(64) void rst_ln_kernel(
    const unsigned short* __restrict__ feat, const float* __restrict__ ent,
    const float* __restrict__ g, const float* __restrict__ b,
    float* __restrict__ rst, unsigned short* __restrict__ y)
{
    int row = blockIdx.x;
    int tid = threadIdx.x;
    const float4 f = bf4(*(const ushort4*)(feat + (size_t)row * FDIM + tid * 4));
    const float4 e = *(const float4*)(ent + (size_t)row * FDIM + tid * 4);
    float4 r;
    r.x = f.x + e.x; r.y = f.y + e.y; r.z = f.z + e.z; r.w = f.w + e.w;
    *(float4*)(rst + (size_t)row * FDIM + tid * 4) = r;
    float s = r.x + r.y + r.z + r.w;
    float q = r.x * r.x + r.y * r.y + r.z * r.z + r.w * r.w;
    #pragma unroll
    for (int d = 1; d < 64; d <<= 1) { s += __shfl_xor(s, d); q += __shfl_xor(q, d); }
    float mean = s * (1.0f / FDIM);
    float var  = q * (1.0f / FDIM) - mean * mean;
    float inv  = rsqrtf(var + 1e-5f);
    float4 gg = *(const float4*)(g + tid * 4);
    float4 bb = *(const float4*)(b + tid * 4);
    ushort4 o;
    o.x = f2bf((r.x - mean) * inv * gg.x + bb.x);
    o.y = f2bf((r.y - mean) * inv * gg.y + bb.y);
    o.z = f2bf((r.z - mean) * inv * gg.z + bb.z);
    o.w = f2bf((r.w - mean) * inv * gg.w + bb.w);
    *(ushort4*)(y + (size_t)row * FDIM + tid * 4) = o;
}

// ---------------------------------------------------------------------------
// Fused weight transposes: all 6 fp32[K,N] -> bf16[N,K] in one dispatch.
// Segments: [0,196608) Wh/Wt/We -> WtP; [196608,262144) Wr -> WtR;
// [262144,524288) W1 -> W1t (K=256,N=1024); [524288,786432) W2 -> W2t.
// ---------------------------------------------------------------------------
__global__ void transpose_all_kernel(
    const float* __restrict__ Wh, const float* __restrict__ Wt_,
    const float* __restrict__ We, const float* __restrict__ Wr,
    const float* __restrict__ W1, const float* __restrict__ W2,
    unsigned short* __restrict__ WtP, unsigned short* __restrict__ WtR,
    unsigned short* __restrict__ W1t, unsigned short* __restrict__ W2t)
{
    int idx = blockIdx.x * 256 + threadIdx.x;
    if (idx < 196608) {
        int seg = idx >> 16, r = idx & 65535;
        const float* W = (seg == 0) ? Wh : (seg == 1) ? Wt_ : We;
        int n = r >> 8, k = r & 255;
        WtP[idx] = f2bf(W[k * 256 + n]);
    } else if (idx < 262144) {
        int r = idx - 196608;
        int n = r >> 8, k = r & 255;
        WtR[r] = f2bf(Wr[k * 256 + n]);
    } else if (idx < 524288) {
        int r = idx - 262144;                 // K=256, N=1024
        int n = r >> 8, k = r & 255;
        W1t[r] = f2bf(W1[k * 1024 + n]);
    } else if (idx < 786432) {
        int r = idx - 524288;                 // K=1024, N=256
        int n = r >> 10, k = r & 1023;
        W2t[r] = f2bf(W2[k * 256 + n]);
    }
}

// ---------------------------------------------------------------------------
// bf16 MFMA GEMM (B^T): C[M,N] = A[M,K] @ Bt[N,K]^T  (+bias)(relu)(+add)
// 128x128 tile, 4 waves, 4x4 16x16x32 frags/wave, BK=32.
// Double-buffered LDS + single barrier per K-step + XCD-aware swizzle.
// ---------------------------------------------------------------------------
__global__ __launch_bounds__(256) void mfma_gemm_bt(
    const unsigned short* __restrict__ A, const unsigned short* __restrict__ Bt,
    const float* __restrict__ bias, const float* __restrict__ add,
    float* __restrict__ Cf, unsigned short* __restrict__ Cb,
    int M, int K, int N, int relu)
{
    __shared__ unsigned short As[2][128 * 32];
    __shared__ unsigned short Bs[2][128 * 32];
    int tid  = threadIdx.x;
    int wave = tid >> 6, lane = tid & 63;
    int quad = lane >> 4, l16 = lane & 15;
    int m0, n0;
    xcd_tile(&m0, &n0, 128, 128);
    int wr = (wave >> 1) * 64, wc = (wave & 1) * 64;

    f32x4 acc[4][4] = {};

    int cA = tid, cB = tid + 256;
    int rA0 = cA >> 2, kA0 = (cA & 3) * 8;
    int rB0 = cB >> 2, kB0 = (cB & 3) * 8;
    int rA = m0 + rA0; if (rA >= M) rA = M - 1;
    int rB = m0 + rB0; if (rB >= M) rB = M - 1;
    const unsigned short* gA0 = A + (size_t)rA * K + kA0;
    const unsigned short* gA1 = A + (size_t)rB * K + kB0;
    const unsigned short* gB0 = Bt + (size_t)(n0 + rA0) * K + kA0;
    const unsigned short* gB1 = Bt + (size_t)(n0 + rB0) * K + kB0;

    g2lds16(gA0, As[0] + cA * 8);
    g2lds16(gA1, As[0] + cB * 8);
    g2lds16(gB0, Bs[0] + cA * 8);
    g2lds16(gB1, Bs[0] + cB * 8);
    __syncthreads();

    int cur = 0;
    for (int k0 = 0; k0 < K; k0 += 32) {
        int k1 = k0 + 32;
        if (k1 < K) {
            int nb = cur ^ 1;
            g2lds16(gA0 + k1, As[nb] + cA * 8);
            g2lds16(gA1 + k1, As[nb] + cB * 8);
            g2lds16(gB0 + k1, Bs[nb] + cA * 8);
            g2lds16(gB1 + k1, Bs[nb] + cB * 8);
        }
        short8 af[4], bfr[4];
        #pragma unroll
        for (int i = 0; i < 4; ++i)
            af[i] = *(const short8*)(As[cur] + (wr + i * 16 + l16) * 32 + quad * 8);
        #pragma unroll
        for (int j = 0; j < 4; ++j)
            bfr[j] = *(const short8*)(Bs[cur] + (wc + j * 16 + l16) * 32 + quad * 8);
        #pragma unroll
        for (int i = 0; i < 4; ++i)
            #pragma unroll
            for (int j = 0; j < 4; ++j)
                acc[i][j] = __builtin_amdgcn_mfma_f32_16x16x32_bf16(
                    af[i], bfr[j], acc[i][j], 0, 0, 0);
        __syncthreads();
        cur ^= 1;
    }

    #pragma unroll
    for (int i = 0; i < 4; ++i) {
        #pragma unroll
        for (int j = 0; j < 4; ++j) {
            int col = n0 + wc + j * 16 + l16;
            float bsv = bias ? bias[col] : 0.0f;
            #pragma unroll
            for (int r = 0; r < 4; ++r) {
                int row = m0 + wr + i * 16 + quad * 4 + r;
                if (row < M) {
                    float v = acc[i][j][r] + bsv;
                    if (relu) v = fmaxf(v, 0.0f);
                    if (add)  v += add[(size_t)row * N + col];
                    if (Cf) Cf[(size_t)row * N + col] = v;
                    else    Cb[(size_t)row * N + col] = f2bf(v);
                }
            }
        }
    }
}

// ---------------------------------------------------------------------------
// 64x128-tile variant (small grids / long K, e.g. FFN2): 4 waves, 4x2 frags.
// ---------------------------------------------------------------------------
__global__ __launch_bounds__(256) void mfma_gemm64_bt(
    const unsigned short* __restrict__ A, const unsigned short* __restrict__ Bt,
    const float* __restrict__ bias, const float* __restrict__ add,
    float* __restrict__ Cf, int M, int K, int N)
{
    __shared__ unsigned short As[2][64 * 32];
    __shared__ unsigned short Bs[2][128 * 32];
    int tid  = threadIdx.x;
    int wave = tid >> 6, lane = tid & 63;
    int quad = lane >> 4, l16 = lane & 15;
    int m0, n0;
    xcd_tile(&m0, &n0, 64, 128);
    int wc = wave * 32;

    f32x4 acc[4][2] = {};

    int rA0 = tid >> 2, kA0 = (tid & 3) * 8;
    int cB0 = tid, cB1 = tid + 256;
    int rB0 = cB0 >> 2, kB0 = (cB0 & 3) * 8;
    int rB1 = cB1 >> 2, kB1 = (cB1 & 3) * 8;
    int rA = m0 + rA0; if (rA >= M) rA = M - 1;
    const unsigned short* gA  = A + (size_t)rA * K + kA0;
    const unsigned short* gB0 = Bt + (size_t)(n0 + rB0) * K + kB0;
    const unsigned short* gB1 = Bt + (size_t)(n0 + rB1) * K + kB1;

    g2lds16(gA,  As[0] + tid * 8);
    g2lds16(gB0, Bs[0] + cB0 * 8);
    g2lds16(gB1, Bs[0] + cB1 * 8);
    __syncthreads();

    int cur = 0;
    for (int k0 = 0; k0 < K; k0 += 32) {
        int k1 = k0 + 32;
        if (k1 < K) {
            int nb = cur ^ 1;
            g2lds16(gA + k1,  As[nb] + tid * 8);
            g2lds16(gB0 + k1, Bs[nb] + cB0 * 8);
            g2lds16(gB1 + k1, Bs[nb] + cB1 * 8);
        }
        short8 af[4], bfr[2];
        #pragma unroll
        for (int i = 0; i < 4; ++i)
            af[i] = *(const short8*)(As[cur] + (i * 16 + l16) * 32 + quad * 8);
        #pragma unroll
        for (int j = 0; j < 2; ++j)
            bfr[j] = *(const short8*)(Bs[cur] + (wc + j * 16 + l16) * 32 + quad * 8);
        #pragma unroll
        for (int i = 0; i < 4; ++i)
            #pragma unroll
            for (int j = 0; j < 2; ++j)
                acc[i][j] = __builtin_amdgcn_mfma_f32_16x16x32_bf16(
                    af[i], bfr[j], acc[i][j], 0, 0, 0);
        __syncthreads();
        cur ^= 1;
    }

    #pragma unroll
    for (int i = 0; i < 4; ++i) {
        #pragma unroll
        for (int j = 0; j < 2; ++j) {
            int col = n0 + wc + j * 16 + l16;
            float bsv = bias ? bias[col] : 0.0f;
            #pragma unroll
            for (int r = 0; r < 4; ++r) {
                int row = m0 + i * 16 + quad * 4 + r;
                if (row < M) {
                    float v = acc[i][j][r] + bsv;
                    if (add) v += add[(size_t)row * N + col];
                    Cf[(size_t)row * N + col] = v;
                }
            }
        }
    }
}

// ---------------------------------------------------------------------------
// Graph plumbing: degree count -> 3-phase parallel scan -> scatter
// ---------------------------------------------------------------------------
__global__ void count_kernel(const int* __restrict__ dst, int* __restrict__ deg, int E)
{
    int i = blockIdx.x * blockDim.x + threadIdx.x;
    if (i < E) atomicAdd(&deg[dst[i]], 1);
}

__global__ __launch_bounds__(256) void scan1_kernel(
    const int* __restrict__ deg, int* __restrict__ offsets, int* __restrict__ bsum, int n)
{
    __shared__ int tmp[256];
    int tid = threadIdx.x;
    int i = blockIdx.x * 256 + tid;
    int v = (i < n) ? deg[i] : 0;
    tmp[tid] = v;
    __syncthreads();
    for (int d = 1; d < 256; d <<= 1) {
        int u = (tid >= d) ? tmp[tid - d] : 0;
        __syncthreads();
        tmp[tid] += u;
        __syncthreads();
    }
    if (i < n) offsets[i] = tmp[tid] - v;
    if (tid == 255) bsum[blockIdx.x] = tmp[255];
}

__global__ __launch_bounds__(128) void scan2_kernel(int* __restrict__ bsum, int nb)
{
    __shared__ int tmp[128];
    int tid = threadIdx.x;
    int v = (tid < nb) ? bsum[tid] : 0;
    tmp[tid] = v;
    __syncthreads();
    for (int d = 1; d < 128; d <<= 1) {
        int u = (tid >= d) ? tmp[tid - d] : 0;
        __syncthreads();
        tmp[tid] += u;
        __syncthreads();
    }
    if (tid < nb) bsum[tid] = tmp[tid] - v;
}

__global__ __launch_bounds__(256) void scan3_kernel(
    const int* __restrict__ deg, int* __restrict__ offsets,
    const int* __restrict__ bsum, int* __restrict__ cursor,
    float* __restrict__ logdeg, int n, int E)
{
    int i = blockIdx.x * 256 + threadIdx.x;
    if (i < n) {
        int o = offsets[i] + bsum[blockIdx.x];
        offsets[i] = o;
        cursor[i]  = o;
        logdeg[i]  = logf((float)deg[i]);
    }
    if (i == 0) offsets[n] = E;
}

__global__ void scatter_kernel(const int* __restrict__ dst, const int* __restrict__ src,
                               const int* __restrict__ rid, int* __restrict__ cursor,
                               int* __restrict__ csr_src, int* __restrict__ csr_rid, int E)
{
    int i = blockIdx.x * blockDim.x + threadIdx.x;
    if (i < E) {
        int p = atomicAdd(&cursor[dst[i]], 1);
        csr_src[p] = src[i];
        csr_rid[p] = rid[i];
    }
}

// ---------------------------------------------------------------------------
// CSR edge attention (r1-proven structure). One wave per dst node (4/block),
// 16 lanes per edge, 8 edges per wave in flight. Stores unnormalized exp;
// writes 1/denom per (node,head) for diffuse (saves the 20 MB re-read pass).
// ---------------------------------------------------------------------------
__global__ __launch_bounds__(256) void edge_score_csr_kernel(
    const unsigned short* __restrict__ proj,   // [N,768]: fh | ftl | fen
    const unsigned short* __restrict__ frel,   // [R,256] bf16
    const float* __restrict__ attn,
    const int* __restrict__ csr_src, const int* __restrict__ csr_rid,
    const int* __restrict__ offsets, const float* __restrict__ logdeg,
    float* __restrict__ csr_a, float* __restrict__ invd, int n)
{
    int node = blockIdx.x * 4 + (threadIdx.x >> 6);
    if (node >= n) return;
    int tid = threadIdx.x & 63;
    int g = tid >> 4, li = tid & 15;
    int start = offsets[node], end = offsets[node + 1];
    float scale = logdeg[node] * (1.0f / 32.0f);

    float tv[16], at[16];
    {
        const unsigned short* tp = proj + (size_t)node * 768 + 256 + li * 16;
        uint4 a0 = *(const uint4*)tp, a1 = *(const uint4*)(tp + 8);
        unpack8(tv, a0); unpack8(tv + 8, a1);
        const float4* ap = (const float4*)(attn + li * 16);
        float4 f;
        f = ap[0]; at[0] = f.x; at[1] = f.y; at[2]  = f.z; at[3]  = f.w;
        f = ap[1]; at[4] = f.x; at[5] = f.y; at[6]  = f.z; at[7]  = f.w;
        f = ap[2]; at[8] = f.x; at[9] = f.y; at[10] = f.z; at[11] = f.w;
        f = ap[3]; at[12] = f.x; at[13] = f.y; at[14] = f.z; at[15] = f.w;
    }

    float denom = 0.f;
    for (int p = start; p < end; p += 8) {
        int  pe[2]; bool va[2]; uint4 h0[2], h1[2], r0[2], r1[2];
        #pragma unroll
        for (int t = 0; t < 2; ++t) {
            pe[t] = p + t * 4 + g;
            va[t] = pe[t] < end;
            int q = va[t] ? pe[t] : end - 1;
            int s = csr_src[q], r = csr_rid[q];
            const unsigned short* hp = proj + (size_t)s * 768 + li * 16;
            const unsigned short* rp = frel + (size_t)r * FDIM + li * 16;
            h0[t] = *(const uint4*)hp; h1[t] = *(const uint4*)(hp + 8);
            r0[t] = *(const uint4*)rp; r1[t] = *(const uint4*)(rp + 8);
        }
        #pragma unroll
        for (int t = 0; t < 2; ++t) {
            float hv[16], rv[16];
            unpack8(hv, h0[t]); unpack8(hv + 8, h1[t]);
            unpack8(rv, r0[t]); unpack8(rv + 8, r1[t]);
            float sum = 0.f;
            #pragma unroll
            for (int k = 0; k < 16; ++k) {
                float m = hv[k] * tv[k] * rv[k];
                m = (m > 0.f) ? m : 0.2f * m;
                sum += m * at[k];
            }
            sum += __shfl_xor(sum, 1);
            float ex = __expf(sum * scale);
            if (va[t] && ((li & 1) == 0)) {
                csr_a[(size_t)pe[t] * NHEAD + (li >> 1)] = ex;
                denom += ex;
            }
        }
    }
    denom += __shfl_xor(denom, 16);
    denom += __shfl_xor(denom, 32);
    if (g == 0 && (li & 1) == 0)
        invd[node * NHEAD + (li >> 1)] = 1.0f / denom;
}

// ---------------------------------------------------------------------------
// One PPR hop (bf16) — r1-proven structure. One wave per dst node (4/block);
// 16 lanes per edge, 16 edges in flight; cross-group reduce once/node.
// Normalization applied once at the end via invd (linear => identical math).
// ---------------------------------------------------------------------------
__global__ __launch_bounds__(256) void diffuse_kernel(
    const unsigned short* __restrict__ fin, int fin_stride,
    const unsigned short* __restrict__ feat0,   // stride 768 (fen in proj)
    const float* __restrict__ a, const float* __restrict__ invd,
    const int* __restrict__ csr_src,
    const int* __restrict__ offsets, unsigned short* __restrict__ fout, int n)
{
    int node = blockIdx.x * 4 + (threadIdx.x >> 6);
    if (node >= n) return;
    int tid = threadIdx.x & 63;
    int g = tid >> 4, li = tid & 15;
    int hh = li >> 1;
    int start = offsets[node], end = offsets[node + 1];
    float wnorm = invd[node * NHEAD + hh];
    float acc[16] = {};

    for (int p = start; p < end; p += 16) {
        uint4 u0[4], u1[4]; float w[4];
        #pragma unroll
        for (int t = 0; t < 4; ++t) {
            int pe = p + t * 4 + g;
            int q = (pe < end) ? pe : end - 1;
            int s = csr_src[q];
            w[t] = (pe < end) ? a[(size_t)q * NHEAD + hh] : 0.0f;
            const unsigned short* rp = fin + (size_t)s * fin_stride + li * 16;
            u0[t] = *(const uint4*)(rp);
            u1[t] = *(const uint4*)(rp + 8);
        }
        #pragma unroll
        for (int t = 0; t < 4; ++t) {
            fma8(acc + 0, u0[t], w[t]);
            fma8(acc + 8, u1[t], w[t]);
        }
    }
    #pragma unroll
    for (int k = 0; k < 16; ++k) {
        acc[k] += __shfl_xor(acc[k], 16);
        acc[k] += __shfl_xor(acc[k], 32);
    }
    if (g == 0) {
        const unsigned short* f0p = feat0 + (size_t)node * 768 + li * 16;
        uint4 f0a = *(const uint4*)(f0p);
        uint4 f0b = *(const uint4*)(f0p + 8);
        float f0[16];
        unpack8(f0, f0a); unpack8(f0 + 8, f0b);
        unsigned short o[16];
        #pragma unroll
        for (int k = 0; k < 16; ++k)
            o[k] = f2bf(0.9f * acc[k] * wnorm + 0.1f * f0[k]);
        uint4* dst4 = (uint4*)(fout + (size_t)node * FDIM + li * 16);
        dst4[0] = *(uint4*)(o);
        dst4[1] = *(uint4*)(o + 8);
    }
}

// ---------------------------------------------------------------------------
extern "C" void kernel_launch(void* const* d_in, const int* in_sizes, int n_in,
                              void* d_out, int out_size, void* d_ws, size_t ws_size,
                              hipStream_t stream)
{
    const float* ent_feat = (const float*)d_in[0];
    const float* rel_feat = (const float*)d_in[1];
    const float* W_head   = (const float*)d_in[2];
    const float* W_tail   = (const float*)d_in[3];
    const float* W_ent    = (const float*)d_in[4];
    const float* W_rel    = (const float*)d_in[5];
    const float* attn     = (const float*)d_in[6];
    const float* ln_ent_g = (const float*)d_in[7];
    const float* ln_ent_b = (const float*)d_in[8];
    const float* ln_rel_g = (const float*)d_in[9];
    const float* ln_rel_b = (const float*)d_in[10];
    const float* ln_ff_g  = (const float*)d_in[11];
    const float* ln_ff_b  = (const float*)d_in[12];
    const float* W1       = (const float*)d_in[13];
    const float* b1       = (const float*)d_in[14];
    const float* W2       = (const float*)d_in[15];
    const float* b2       = (const float*)d_in[16];
    const int*   src      = (const int*)d_in[17];
    const int*   dst      = (const int*)d_in[18];
    const int*   rid      = (const int*)d_in[19];
    float* out = (float*)d_out;

    // ---- workspace carve (bytes, 256-aligned) ----
    char* base = (char*)d_ws;
    auto carve = [&](size_t bytes) { char* p = base; base += (bytes + 255) & ~(size_t)255; return p; };
    unsigned short* xb    = (unsigned short*)carve((size_t)N_NODES * FDIM * 2);
    unsigned short* projb = (unsigned short*)carve((size_t)N_NODES * 768 * 2);
    unsigned short* rlnb  = (unsigned short*)carve((size_t)N_REL * FDIM * 2);
    unsigned short* frelb = (unsigned short*)carve((size_t)N_REL * FDIM * 2);
    unsigned short* WtP   = (unsigned short*)carve((size_t)768 * FDIM * 2);
    unsigned short* WtR   = (unsigned short*)carve((size_t)FDIM * FDIM * 2);
    unsigned short* W1t   = (unsigned short*)carve((size_t)1024 * FDIM * 2);
    unsigned short* W2t   = (unsigned short*)carve((size_t)FDIM * 1024 * 2);
    unsigned short* hb0   = (unsigned short*)carve((size_t)N_NODES * FDIM * 2);
    unsigned short* hb1   = (unsigned short*)carve((size_t)N_NODES * FDIM * 2);
    unsigned short* yb    = (unsigned short*)carve((size_t)N_NODES * FDIM * 2);
    unsigned short* t1b   = (unsigned short*)carve((size_t)N_NODES * 1024 * 2);
    float* rst     = (float*)carve((size_t)N_NODES * FDIM * 4);
    float* csr_a   = (float*)carve(((size_t)N_EDGES * NHEAD + 256) * 4);
    float* invd    = (float*)carve((size_t)N_NODES * NHEAD * 4);
    int*   csr_src = (int*)carve((size_t)(N_EDGES + 64) * 4);
    int*   csr_rid = (int*)carve((size_t)(N_EDGES + 64) * 4);
    int*   deg     = (int*)carve((size_t)N_NODES * 4);
    float* logdeg  = (float*)carve((size_t)N_NODES * 4);
    int*   offsets = (int*)carve((size_t)(N_NODES + 1) * 4);
    int*   cursor  = (int*)carve((size_t)N_NODES * 4);
    int*   bsum    = (int*)carve((size_t)SCAN_BLOCKS * 4);

    hipMemsetAsync(deg, 0, (size_t)N_NODES * 4, stream);

    // fused LN -> bf16 (node + rel rows in one grid)
    ln_fused_kernel<<<N_NODES + N_REL, 64, 0, stream>>>(
        ent_feat, rel_feat, ln_ent_g, ln_ent_b, ln_rel_g, ln_rel_b, xb, rlnb);

    // fused weight transposes (6 matrices, 1 dispatch)
    transpose_all_kernel<<<786432 / 256, 256, 0, stream>>>(
        W_head, W_tail, W_ent, W_rel, W1, W2, WtP, WtR, W1t, W2t);

    // fused projection GEMM: proj[N,768] = xb @ [Wh|Wt|We]  (bf16 out)
    dim3 gproj((N_NODES + 127) / 128, 768 / 128);
    mfma_gemm_bt<<<gproj, 256, 0, stream>>>(xb, WtP, nullptr, nullptr, nullptr, projb,
                                            N_NODES, FDIM, 768, 0);
    dim3 grel(1, FDIM / 128);
    mfma_gemm_bt<<<grel, 256, 0, stream>>>(rlnb, WtR, nullptr, nullptr, nullptr, frelb,
                                           N_REL, FDIM, FDIM, 0);

    // CSR build (count -> 3-phase parallel scan -> scatter)
    count_kernel<<<(N_EDGES + 255) / 256, 256, 0, stream>>>(dst, deg, N_EDGES);
    scan1_kernel<<<SCAN_BLOCKS, 256, 0, stream>>>(deg, offsets, bsum, N_NODES);
    scan2_kernel<<<1, 128, 0, stream>>>(bsum, SCAN_BLOCKS);
    scan3_kernel<<<SCAN_BLOCKS, 256, 0, stream>>>(deg, offsets, bsum, cursor, logdeg,
                                                  N_NODES, N_EDGES);
    scatter_kernel<<<(N_EDGES + 255) / 256, 256, 0, stream>>>(dst, src, rid, cursor,
                                                              csr_src, csr_rid, N_EDGES);

    // attention scores (unnormalized exp) + per-(node,head) 1/denom
    edge_score_csr_kernel<<<(N_NODES + 3) / 4, 256, 0, stream>>>(
        projb, frelb, attn, csr_src, csr_rid, offsets, logdeg, csr_a, invd, N_NODES);

    // 5-hop PPR diffusion (bf16): fen(proj+512) -> hb0 -> hb1 -> hb0 -> hb1 -> hb0
    const unsigned short* fen = projb + 512;
    int gdif = (N_NODES + 3) / 4;
    diffuse_kernel<<<gdif, 256, 0, stream>>>(fen, 768, fen, csr_a, invd, csr_src, offsets, hb0, N_NODES);
    diffuse_kernel<<<gdif, 256, 0, stream>>>(hb0, FDIM, fen, csr_a, invd, csr_src, offsets, hb1, N_NODES);
    diffuse_kernel<<<gdif, 256, 0, stream>>>(hb1, FDIM, fen, csr_a, invd, csr_src, offsets, hb0, N_NODES);
    diffuse_kernel<<<gdif, 256, 0, stream>>>(hb0, FDIM, fen, csr_a, invd, csr_src, offsets, hb1, N_NODES);
    diffuse_kernel<<<gdif, 256, 0, stream>>>(hb1, FDIM, fen, csr_a, invd, csr_src, offsets, hb0, N_NODES);

    // residual + pre-LN
    rst_ln_kernel<<<N_NODES, 64, 0, stream>>>(hb0, ent_feat, ln_ff_g, ln_ff_b, rst, yb);

    // FFN1: t1 = relu(y@W1 + b1) [bf16], 128x128 tiles
    dim3 gff1((N_NODES + 127) / 128, 1024 / 128);
    mfma_gemm_bt<<<gff1, 256, 0, stream>>>(yb, W1t, b1, nullptr, nullptr, t1b,
                                           N_NODES, FDIM, 1024, 1);
    // FFN2: out = t1@W2 + b2 + rst, 64x128 tiles
    dim3 gff2((N_NODES + 63) / 64, FDIM / 128);
    mfma_gemm64_bt<<<gff2, 256, 0, stream>>>(t1b, W2t, b2, rst, out,
                                             N_NODES, 1024, FDIM);
}